// Round 10
// baseline (976.458 us; speedup 1.0000x reference)
//
#include <hip/hip_runtime.h>
#include <hip/hip_fp16.h>
#include <math.h>
#include <stdint.h>

#define DIM 10
#define NTILE 256
#define BKT_LOG 8
#define BKT 256                   // nodes per bucket
#define NBMAX 2048
#define EPW 32768                 // edges per WG in binning
#define CHUNK 2048
#define KPT (CHUNK / 256)         // 8 edges per thread per chunk
#define NCHUNK (EPW / CHUNK)      // 16
#define CAPB 2556                 // bin slots per bucket (NB*CAPB <= out_size)
#define CAPF 1152                 // front region (edges useful at iter 1)
#define CAPK (CAPB - CAPF)        // back region (iter-0-only edges)
#define OVFCAP 32768
#define NPART 32
#define PSHIFT 14                 // send-partition = s >> 14

// meta (u32) in ws after x,h32,h16: cntF[2048] | cntB[2048] | ovfc[8] | ovf[OVFCAP]

__global__ void meta_zero_kernel(uint32_t* __restrict__ meta, int tot) {
    int i = blockIdx.x * blockDim.x + threadIdx.x;
    if (i < tot) meta[i] = 0;
}

__device__ __forceinline__ float2 cvt2(uint32_t u) {
    __half2 hh = *reinterpret_cast<__half2*>(&u);
    return __half22float2(hh);
}

// ---------------------------------------------------------------------------
// binning: EPW=32768 per WG (16 chunks), two passes (histogram, emit) so that
// each WG writes ~9 contiguous slots per bucket -> bin-write lines amortized.
// word = s(19b) | rl(8b)<<19 | flag<<27
// ---------------------------------------------------------------------------
__global__ __launch_bounds__(256) void bin_kernel(
                           const int* __restrict__ recv,
                           const int* __restrict__ send,
                           const int* __restrict__ depth,
                           uint32_t* __restrict__ cntF,
                           uint32_t* __restrict__ cntB,
                           uint32_t* __restrict__ ovfc,
                           uint32_t* __restrict__ ovf,
                           uint32_t* __restrict__ bins,
                           int ne)
{
    __shared__ uint32_t lh[NBMAX];     // front lo16 | back hi16
    __shared__ uint32_t wgF[NBMAX];
    __shared__ uint32_t wgB[NBMAX];
    __shared__ uint32_t lcur[NBMAX];
    const int t = threadIdx.x;
    for (int i = t; i < NBMAX; i += 256) lh[i] = 0;
    __syncthreads();

    const int base0 = blockIdx.x * EPW;

    // ---- pass 1: histogram ----
    for (int ch = 0; ch < NCHUNK; ++ch) {
        const int base = base0 + ch * CHUNK;
        int rA[KPT], sA[KPT];
        #pragma unroll
        for (int k = 0; k < KPT; ++k) {
            int e = base + k * 256 + t;
            if (e < ne) { rA[k] = recv[e]; sA[k] = send[e]; }
            else        { rA[k] = -1;      sA[k] = 0;       }
        }
        int drA[KPT], dsA[KPT];
        #pragma unroll
        for (int k = 0; k < KPT; ++k) {
            if (rA[k] >= 0) { drA[k] = depth[rA[k]]; dsA[k] = depth[sA[k]]; }
            else            { drA[k] = 99;           dsA[k] = 99;           }
        }
        #pragma unroll
        for (int k = 0; k < KPT; ++k) {
            if (drA[k] <= 2 && dsA[k] <= 2) {
                bool f1 = (drA[k] <= 1) && (dsA[k] <= 1);
                atomicAdd(&lh[rA[k] >> BKT_LOG], f1 ? 1u : 0x10000u);
            }
        }
    }
    __syncthreads();

    // ---- reserve global ranges ----
    for (int i = t; i < NBMAX; i += 256) {
        uint32_t v = lh[i];
        lcur[i] = 0;
        if (v) {
            uint32_t f = v & 0xffffu, kb = v >> 16;
            if (f)  wgF[i] = atomicAdd(&cntF[i], f);
            if (kb) wgB[i] = atomicAdd(&cntB[i], kb);
        }
    }
    __syncthreads();

    // ---- pass 2: emit ----
    for (int ch = 0; ch < NCHUNK; ++ch) {
        const int base = base0 + ch * CHUNK;
        int rA[KPT], sA[KPT];
        #pragma unroll
        for (int k = 0; k < KPT; ++k) {
            int e = base + k * 256 + t;
            if (e < ne) { rA[k] = recv[e]; sA[k] = send[e]; }
            else        { rA[k] = -1;      sA[k] = 0;       }
        }
        int drA[KPT], dsA[KPT];
        #pragma unroll
        for (int k = 0; k < KPT; ++k) {
            if (rA[k] >= 0) { drA[k] = depth[rA[k]]; dsA[k] = depth[sA[k]]; }
            else            { drA[k] = 99;           dsA[k] = 99;           }
        }
        #pragma unroll
        for (int k = 0; k < KPT; ++k) {
            if (drA[k] <= 2 && dsA[k] <= 2) {
                int r = rA[k], s = sA[k];
                int b = r >> BKT_LOG;
                bool f1 = (drA[k] <= 1) && (dsA[k] <= 1);
                uint32_t w = (uint32_t)s | ((uint32_t)(r & (BKT - 1)) << 19)
                           | (f1 ? (1u << 27) : 0u);
                if (f1) {
                    uint32_t o = atomicAdd(&lcur[b], 1u) & 0xffffu;
                    uint32_t pos = wgF[b] + o;
                    if (pos < CAPF) bins[(size_t)b * CAPB + pos] = w;
                    else { uint32_t oi = atomicAdd(ovfc, 1u);
                           if (oi < OVFCAP) ovf[oi] = (uint32_t)(base + k * 256 + t); }
                } else {
                    uint32_t o = atomicAdd(&lcur[b], 0x10000u) >> 16;
                    uint32_t pos = wgB[b] + o;
                    if (pos < CAPK) bins[(size_t)b * CAPB + (CAPB - 1) - pos] = w;
                    else { uint32_t oi = atomicAdd(ovfc, 1u);
                           if (oi < OVFCAP) ovf[oi] = (uint32_t)(base + k * 256 + t); }
                }
            }
        }
    }
}

// ---------------------------------------------------------------------------
// scatter: one WG per 256-node bucket; partition-sort (send>>14) in LDS;
// fp16 h-gather (32-B records, 1 line/row, 2 rows/line); fp32 LDS accumulate.
// ---------------------------------------------------------------------------
template<int ITER>
__global__ __launch_bounds__(256) void scat_kernel(
                            const uint32_t* __restrict__ bins,
                            const uint32_t* __restrict__ cntF,
                            const uint32_t* __restrict__ cntB,
                            const uint16_t* __restrict__ h16,  // stride 16 halfs
                            float* __restrict__ x,             // stride 10
                            int n)
{
    __shared__ float xl[BKT * DIM];      // 10240 B
    __shared__ uint32_t ewB[CAPB];       // 10224 B (partition-sorted)
    __shared__ uint32_t hist[NPART];
    __shared__ uint32_t hoff[NPART];

    const int t = threadIdx.x;
    const int b = blockIdx.x;
    const int n0 = b << BKT_LOG;
    const int nb = min(BKT, n - n0);

    for (int i = t; i < BKT * DIM; i += 256) xl[i] = 0.0f;
    if (t < NPART) hist[t] = 0;
    __syncthreads();

    const size_t base = (size_t)b * CAPB;
    const int fc = (int)min(cntF[b], (uint32_t)CAPF);
    int tot = fc, boff = 0;
    if (ITER == 0) {
        int bc = (int)min(cntB[b], (uint32_t)CAPK);
        tot = fc + bc;
        boff = CAPB - bc - fc;
    }

    // pass 1: histogram partitions
    for (int i = t; i < tot; i += 256) {
        size_t idx = base + (size_t)((ITER == 0 && i >= fc) ? (i + boff) : i);
        uint32_t w = bins[idx];
        atomicAdd(&hist[(w & 0x7FFFFu) >> PSHIFT], 1u);
    }
    __syncthreads();
    if (t == 0) {
        uint32_t acc = 0;
        #pragma unroll
        for (int p = 0; p < NPART; ++p) { hoff[p] = acc; acc += hist[p]; }
    }
    __syncthreads();
    // pass 2: permute into ewB (bins 2nd read is L2-hot)
    for (int i = t; i < tot; i += 256) {
        size_t idx = base + (size_t)((ITER == 0 && i >= fc) ? (i + boff) : i);
        uint32_t w = bins[idx];
        uint32_t o = atomicAdd(&hoff[(w & 0x7FFFFu) >> PSHIFT], 1u);
        ewB[o] = w;
    }
    __syncthreads();

    // pass 3: fp16 gather + LDS accumulate (K=4 batching)
    for (int i0 = t; i0 < tot; i0 += 256 * 4) {
        uint32_t w[4];
        bool v[4];
        #pragma unroll
        for (int k = 0; k < 4; ++k) {
            int i = i0 + k * 256;
            v[k] = (i < tot);
            if (v[k]) w[k] = ewB[i];
        }
        uint4 q[4]; uint32_t e8[4];
        #pragma unroll
        for (int k = 0; k < 4; ++k) {
            if (v[k]) {
                size_t s = (size_t)(w[k] & 0x7FFFFu);
                q[k]  = *reinterpret_cast<const uint4*>(h16 + s * 16);
                e8[k] = *reinterpret_cast<const uint32_t*>(h16 + s * 16 + 8);
            }
        }
        #pragma unroll
        for (int k = 0; k < 4; ++k) {
            if (v[k]) {
                float2 f0 = cvt2(q[k].x), f1 = cvt2(q[k].y);
                float2 f2 = cvt2(q[k].z), f3 = cvt2(q[k].w);
                float2 f4 = cvt2(e8[k]);
                uint32_t rl = (w[k] >> 19) & (BKT - 1);
                float* xr = xl + rl * DIM;
                atomicAdd(xr + 0, f0.x); atomicAdd(xr + 1, f0.y);
                atomicAdd(xr + 2, f1.x); atomicAdd(xr + 3, f1.y);
                atomicAdd(xr + 4, f2.x); atomicAdd(xr + 5, f2.y);
                atomicAdd(xr + 6, f3.x); atomicAdd(xr + 7, f3.y);
                atomicAdd(xr + 8, f4.x); atomicAdd(xr + 9, f4.y);
            }
        }
    }
    __syncthreads();

    float* xo = x + (size_t)n0 * DIM;
    for (int i = t; i < nb * DIM; i += 256) xo[i] = xl[i];
}

// ---------------------------------------------------------------------------
// spilled edges: exact fp32 path via global HW atomics (count ~O(100))
// ---------------------------------------------------------------------------
__global__ void ovf_apply_kernel(const uint32_t* __restrict__ ovfc,
                                 const uint32_t* __restrict__ ovf,
                                 const int* __restrict__ recv,
                                 const int* __restrict__ send,
                                 const int* __restrict__ depth,
                                 const float* __restrict__ h32,  // stride 10
                                 float* __restrict__ x,          // stride 10
                                 int iter)
{
    const uint32_t cnt = min(*ovfc, (uint32_t)OVFCAP);
    for (uint32_t i = blockIdx.x * blockDim.x + threadIdx.x; i < cnt;
         i += gridDim.x * blockDim.x) {
        int e = (int)ovf[i];
        int r = recv[e], s = send[e];
        if (iter == 1 && (depth[r] > 1 || depth[s] > 1)) continue;
        const float* hr = h32 + (size_t)s * DIM;
        float* xr = x + (size_t)r * DIM;
        #pragma unroll
        for (int c = 0; c < DIM; ++c) unsafeAtomicAdd(xr + c, hr[c]);
    }
}

// ---------------------------------------------------------------------------
// init: h32[node] = (depth<=2)? h_in[node] : 0  (stride 10)
//       h16[node] = half(h32[node])             (stride 16 halfs, pads 0)
// ---------------------------------------------------------------------------
__global__ void init_mask_kernel(const float* __restrict__ hsrc,
                                 float* __restrict__ h32,
                                 uint16_t* __restrict__ h16,
                                 const int* __restrict__ depth,
                                 int n)
{
    __shared__ float sh[NTILE * 11];
    const int t = threadIdx.x;
    const int base = blockIdx.x * NTILE;

    const long gbase = (long)base * DIM;
    const long glim  = (long)n * DIM;
    for (int idx = t; idx < NTILE * DIM; idx += NTILE) {
        long g = gbase + idx;
        float v = (g < glim) ? hsrc[g] : 0.0f;
        sh[(idx / DIM) * 11 + (idx % DIM)] = v;
    }
    __syncthreads();

    const int node = base + t;
    if (node < n && depth[node] > 2) {
        #pragma unroll
        for (int c = 0; c < DIM; ++c) sh[t * 11 + c] = 0.0f;
    }
    __syncthreads();

    // write h32 (stride 10, coalesced)
    for (int idx = t; idx < NTILE * DIM; idx += NTILE) {
        long g = gbase + idx;
        if (g < glim) h32[g] = sh[(idx / DIM) * 11 + (idx % DIM)];
    }
    // write h16 (8 uints per node, coalesced); skipped when not provided
    if (h16 != nullptr) {
        uint32_t* o16 = reinterpret_cast<uint32_t*>(h16);
        const long o16base = (long)base * 8;
        const long o16lim  = (long)n * 8;
        for (int idx = t; idx < NTILE * 8; idx += NTILE) {
            long g = o16base + idx;
            if (g < o16lim) {
                int nl = idx / 8, c2 = idx % 8;
                uint32_t w = 0;
                if (c2 < 5) {
                    __half2 hh = __floats2half2_rn(sh[nl * 11 + 2 * c2],
                                                   sh[nl * 11 + 2 * c2 + 1]);
                    w = *reinterpret_cast<uint32_t*>(&hh);
                }
                o16[g] = w;
            }
        }
    }
}

// ---------------------------------------------------------------------------
// GRU update, LDS tile-staged; x,h stride 10; out32 stride 10 (+optional h16)
// ---------------------------------------------------------------------------
template<int NEXTMASK, int WRITE16>
__global__ void gru_kernel(const float* __restrict__ x,
                           const float* __restrict__ h,
                           float* __restrict__ out32,
                           uint16_t* __restrict__ out16,
                           const int* __restrict__ depth, int iter, int n,
                           const float* __restrict__ Wz, const float* __restrict__ bz,
                           const float* __restrict__ Uz, const float* __restrict__ buz,
                           const float* __restrict__ Wr, const float* __restrict__ br,
                           const float* __restrict__ Ur, const float* __restrict__ bur,
                           const float* __restrict__ Wh, const float* __restrict__ bh,
                           const float* __restrict__ Uh, const float* __restrict__ buh)
{
    __shared__ float sx[NTILE * 17];
    __shared__ float shh[NTILE * 17];
    __shared__ float sW[6][100];
    __shared__ float sb[3][10];

    const int t = threadIdx.x;
    if (t < 100) {
        sW[0][t] = Wz[t]; sW[1][t] = Uz[t];
        sW[2][t] = Wr[t]; sW[3][t] = Ur[t];
        sW[4][t] = Wh[t]; sW[5][t] = Uh[t];
    }
    if (t < 10) {
        sb[0][t] = bz[t] + buz[t];
        sb[1][t] = br[t] + bur[t];
        sb[2][t] = bh[t] + buh[t];
    }

    const int base = blockIdx.x * NTILE;

    {   // stage x tile (stride 10, float4)
        const int tile4 = NTILE * DIM / 4;
        const long g4base = (long)base * DIM / 4;
        const long g4lim  = (long)n * DIM / 4;
        const float4* xg = reinterpret_cast<const float4*>(x);
        for (int i4 = t; i4 < tile4; i4 += NTILE) {
            long g = g4base + i4;
            if (g < g4lim) {
                float4 v = xg[g];
                float vv[4] = {v.x, v.y, v.z, v.w};
                int f = i4 * 4;
                int nl = f / DIM, c = f % DIM;
                #pragma unroll
                for (int k = 0; k < 4; ++k) {
                    sx[nl * 17 + c] = vv[k];
                    if (++c == DIM) { c = 0; ++nl; }
                }
            }
        }
    }
    {   // stage h tile (stride 10, float4)
        const int tile4 = NTILE * DIM / 4;
        const long g4base = (long)base * DIM / 4;
        const long g4lim  = (long)n * DIM / 4;
        const float4* hg = reinterpret_cast<const float4*>(h);
        for (int i4 = t; i4 < tile4; i4 += NTILE) {
            long g = g4base + i4;
            if (g < g4lim) {
                float4 v = hg[g];
                float vv[4] = {v.x, v.y, v.z, v.w};
                int f = i4 * 4;
                int nl = f / DIM, c = f % DIM;
                #pragma unroll
                for (int k = 0; k < 4; ++k) {
                    shh[nl * 17 + c] = vv[k];
                    if (++c == DIM) { c = 0; ++nl; }
                }
            }
        }
    }
    __syncthreads();

    const int node = base + t;
    const bool valid = node < n;
    const int dep = valid ? depth[node] : 99;
    const bool active = valid && (dep + iter <= 2);

    float xv[DIM], hv[DIM], outv[DIM];
    #pragma unroll
    for (int j = 0; j < DIM; ++j) {
        xv[j] = sx[t * 17 + j];
        hv[j] = shh[t * 17 + j];
    }

    if (active) {
        float zz[DIM], rr[DIM];
        #pragma unroll
        for (int i = 0; i < DIM; ++i) {
            float az = sb[0][i];
            float ar = sb[1][i];
            #pragma unroll
            for (int j = 0; j < DIM; ++j) {
                az = fmaf(xv[j], sW[0][i * DIM + j], az);
                az = fmaf(hv[j], sW[1][i * DIM + j], az);
                ar = fmaf(xv[j], sW[2][i * DIM + j], ar);
                ar = fmaf(hv[j], sW[3][i * DIM + j], ar);
            }
            zz[i] = 1.0f / (1.0f + __expf(-az));
            rr[i] = 1.0f / (1.0f + __expf(-ar));
        }
        float rh[DIM];
        #pragma unroll
        for (int j = 0; j < DIM; ++j) rh[j] = rr[j] * hv[j];
        #pragma unroll
        for (int i = 0; i < DIM; ++i) {
            float ah = sb[2][i];
            #pragma unroll
            for (int j = 0; j < DIM; ++j) {
                ah = fmaf(xv[j], sW[4][i * DIM + j], ah);
                ah = fmaf(rh[j], sW[5][i * DIM + j], ah);
            }
            float th = tanhf(ah);
            outv[i] = zz[i] * hv[i] + (1.0f - zz[i]) * th;
        }
    } else {
        #pragma unroll
        for (int i = 0; i < DIM; ++i) outv[i] = hv[i];   // inactive: h already 0
    }

    if (NEXTMASK) {
        const bool keep = valid && (dep + iter + 1 <= 2);
        if (!keep) {
            #pragma unroll
            for (int i = 0; i < DIM; ++i) outv[i] = 0.0f;
        }
    }

    __syncthreads();
    #pragma unroll
    for (int i = 0; i < DIM; ++i) sx[t * 17 + i] = outv[i];
    __syncthreads();

    // flush out32 (stride 10)
    const long obase = (long)base * DIM;
    const long olim  = (long)n * DIM;
    for (int idx = t; idx < NTILE * DIM; idx += NTILE) {
        long g = obase + idx;
        if (g < olim) out32[g] = sx[(idx / DIM) * 17 + (idx % DIM)];
    }
    // flush out16 (stride 16 halfs)
    if (WRITE16) {
        uint32_t* o16 = reinterpret_cast<uint32_t*>(out16);
        const long o16base = (long)base * 8;
        const long o16lim  = (long)n * 8;
        for (int idx = t; idx < NTILE * 8; idx += NTILE) {
            long g = o16base + idx;
            if (g < o16lim) {
                int nl = idx / 8, c2 = idx % 8;
                uint32_t w = 0;
                if (c2 < 5) {
                    __half2 hh = __floats2half2_rn(sx[nl * 17 + 2 * c2],
                                                   sx[nl * 17 + 2 * c2 + 1]);
                    w = *reinterpret_cast<uint32_t*>(&hh);
                }
                o16[g] = w;
            }
        }
    }
}

// ---------------------------------------------------------------------------
// fallback simple atomic scatter (only if ws too small / n too large)
// ---------------------------------------------------------------------------
__global__ void simple_scatter_kernel(const int* __restrict__ recv,
                                      const int* __restrict__ send,
                                      const float* __restrict__ hm,  // stride 10
                                      float* __restrict__ x,         // stride 10
                                      int ne)
{
    const int tid = blockIdx.x * blockDim.x + threadIdx.x;
    const int e = tid / DIM;
    if (e >= ne) return;
    const int c = tid - e * DIM;
    const int s = send[e];
    const float v = hm[(size_t)s * DIM + c];
    if (v != 0.0f) {
        const int r = recv[e];
        unsafeAtomicAdd(x + (size_t)r * DIM + c, v);
    }
}

__global__ void zero_buf_kernel(float4* __restrict__ p, int tot4) {
    int i = blockIdx.x * blockDim.x + threadIdx.x;
    if (i < tot4) p[i] = make_float4(0.0f, 0.0f, 0.0f, 0.0f);
}

extern "C" void kernel_launch(void* const* d_in, const int* in_sizes, int n_in,
                              void* d_out, int out_size, void* d_ws, size_t ws_size,
                              hipStream_t stream) {
    const float* h_in  = (const float*)d_in[0];
    const int*   edges = (const int*)d_in[1];
    const int*   depth = (const int*)d_in[2];
    const float* Wz  = (const float*)d_in[3];
    const float* bz  = (const float*)d_in[4];
    const float* Uz  = (const float*)d_in[5];
    const float* buz = (const float*)d_in[6];
    const float* Wr  = (const float*)d_in[7];
    const float* br  = (const float*)d_in[8];
    const float* Ur  = (const float*)d_in[9];
    const float* bur = (const float*)d_in[10];
    const float* Wh  = (const float*)d_in[11];
    const float* bh  = (const float*)d_in[12];
    const float* Uh  = (const float*)d_in[13];
    const float* buh = (const float*)d_in[14];

    const int n  = in_sizes[0] / DIM;       // 500,000
    const int ne = in_sizes[1] / 2;         // 8,000,000
    const int* recv = edges;
    const int* send = edges + ne;

    const int NB = (n + BKT - 1) >> BKT_LOG;
    const size_t meta_words = 2 * NBMAX + 8 + OVFCAP;
    const size_t need = (size_t)n * DIM * sizeof(float) * 2      // x + h32
                      + (size_t)n * 16 * sizeof(uint16_t)        // h16
                      + meta_words * sizeof(uint32_t);

    const int BLK = 256;
    const int node_blocks = (n + NTILE - 1) / NTILE;

    if (ws_size >= need && n <= (1 << 19) && NB <= NBMAX &&
        (size_t)NB * CAPB <= (size_t)out_size) {
        float*    x    = (float*)d_ws;                         // [n*10]
        float*    h32  = (float*)d_ws + (size_t)n * DIM;       // [n*10]
        uint16_t* h16  = (uint16_t*)(h32 + (size_t)n * DIM);   // [n*16]
        uint32_t* meta = (uint32_t*)(h16 + (size_t)n * 16);
        uint32_t* cntF = meta;                // NBMAX
        uint32_t* cntB = meta + NBMAX;        // NBMAX
        uint32_t* ovfc = meta + 2 * NBMAX;    // 8 (1 used)
        uint32_t* ovf  = meta + 2 * NBMAX + 8;
        uint32_t* bins = (uint32_t*)d_out;

        const int meta_tot = 2 * NBMAX + 1;
        const int bin_blocks = (ne + EPW - 1) / EPW;

        meta_zero_kernel<<<(meta_tot + BLK - 1) / BLK, BLK, 0, stream>>>(meta, meta_tot);
        bin_kernel<<<bin_blocks, BLK, 0, stream>>>(recv, send, depth,
                                                   cntF, cntB, ovfc, ovf, bins, ne);
        init_mask_kernel<<<node_blocks, NTILE, 0, stream>>>(h_in, h32, h16, depth, n);

        // ---- iteration 0 (active: depth<=2) ----
        scat_kernel<0><<<NB, BLK, 0, stream>>>(bins, cntF, cntB, h16, x, n);
        ovf_apply_kernel<<<16, BLK, 0, stream>>>(ovfc, ovf, recv, send, depth, h32, x, 0);
        gru_kernel<1, 1><<<node_blocks, NTILE, 0, stream>>>(x, h32, h32, h16, depth, 0, n,
            Wz, bz, Uz, buz, Wr, br, Ur, bur, Wh, bh, Uh, buh);

        // ---- iteration 1 (active: depth<=1) ----
        scat_kernel<1><<<NB, BLK, 0, stream>>>(bins, cntF, cntB, h16, x, n);
        ovf_apply_kernel<<<16, BLK, 0, stream>>>(ovfc, ovf, recv, send, depth, h32, x, 1);
        gru_kernel<0, 0><<<node_blocks, NTILE, 0, stream>>>(x, h32, (float*)d_out, nullptr, depth, 1, n,
            Wz, bz, Uz, buz, Wr, br, Ur, bur, Wh, bh, Uh, buh);
    } else {
        // fallback: unpadded atomic path, h in d_out (h16 disabled)
        float* x    = (float*)d_ws;
        float* hbuf = (float*)d_out;
        const int nwork = ne * DIM;
        const int edge_blocks = (nwork + BLK - 1) / BLK;
        const int x_tot4 = (n * DIM) / 4;
        const int xz_blocks = (x_tot4 + BLK - 1) / BLK;

        init_mask_kernel<<<node_blocks, NTILE, 0, stream>>>(h_in, hbuf, nullptr, depth, n);
        zero_buf_kernel<<<xz_blocks, BLK, 0, stream>>>((float4*)x, x_tot4);
        simple_scatter_kernel<<<edge_blocks, BLK, 0, stream>>>(recv, send, hbuf, x, ne);
        gru_kernel<1, 0><<<node_blocks, NTILE, 0, stream>>>(x, hbuf, hbuf, nullptr, depth, 0, n,
            Wz, bz, Uz, buz, Wr, br, Ur, bur, Wh, bh, Uh, buh);
        zero_buf_kernel<<<xz_blocks, BLK, 0, stream>>>((float4*)x, x_tot4);
        simple_scatter_kernel<<<edge_blocks, BLK, 0, stream>>>(recv, send, hbuf, x, ne);
        gru_kernel<0, 0><<<node_blocks, NTILE, 0, stream>>>(x, hbuf, hbuf, nullptr, depth, 1, n,
            Wz, bz, Uz, buz, Wr, br, Ur, bur, Wh, bh, Uh, buh);
    }
}

// Round 11
// 883.872 us; speedup vs baseline: 1.1048x; 1.1048x over previous
//
#include <hip/hip_runtime.h>
#include <hip/hip_fp16.h>
#include <math.h>
#include <stdint.h>

#define DIM 10
#define NTILE 256
#define BKT_LOG 8
#define BKT 256                   // nodes per bucket
#define NBMAX 2048
#define EPW 2048                  // edges per WG in binning
#define KPT (EPW / 256)           // 8 edges per thread
#define CAPB 2556                 // bin slots per bucket (NB*CAPB <= out_size)
#define CAPF 1152                 // front region (edges useful at iter 1)
#define CAPK (CAPB - CAPF)        // back region (iter-0-only edges)
#define OVFCAP 32768
#define D2WORDS 32768             // packed 2-bit depth table (covers n <= 2^19)

// meta (u32) in ws after x,h32,h16:
//   cntF[2048] | cntB[2048] | ovfc[8] | ovf[OVFCAP] | depth2[D2WORDS]

__global__ void meta_zero_kernel(uint32_t* __restrict__ meta, int tot) {
    int i = blockIdx.x * blockDim.x + threadIdx.x;
    if (i < tot) meta[i] = 0;
}

// ---------------------------------------------------------------------------
// pack depth (0..3) into 2 bits/node: word w holds nodes 16w..16w+15.
// 125 KB table -> L1/L2-resident for bin's random filter gathers.
// ---------------------------------------------------------------------------
__global__ void pack_depth_kernel(const int* __restrict__ depth,
                                  uint32_t* __restrict__ depth2,
                                  int n)
{
    __shared__ int sd[4096];
    const int t = threadIdx.x;
    const int base = blockIdx.x * 4096;
    for (int i = t; i < 4096; i += 256) {
        int g = base + i;
        sd[i] = (g < n) ? depth[g] : 3;
    }
    __syncthreads();
    const int wbase = base >> 4;
    if (t < 256) {
        int wb = wbase + t;
        if (wb * 16 < n) {
            uint32_t v = 0;
            #pragma unroll
            for (int j = 0; j < 16; ++j)
                v |= ((uint32_t)(sd[t * 16 + j] & 3)) << (2 * j);
            depth2[wb] = v;
        }
    }
}

__device__ __forceinline__ float2 cvt2(uint32_t u) {
    __half2 hh = *reinterpret_cast<__half2*>(&u);
    return __half22float2(hh);
}

__device__ __forceinline__ int d2get(const uint32_t* __restrict__ depth2, int node) {
    uint32_t w = depth2[(uint32_t)node >> 4];
    return (int)((w >> ((node & 15) * 2)) & 3u);
}

// ---------------------------------------------------------------------------
// single-pass binning (round-7 structure), filter gathers via packed depth2.
// Bucket b owns bins[b*CAPB .. b*CAPB+CAPB):
//   front [0,CAPF): edges with dr<=1 && ds<=1 (useful both iters)
//   back  (grows from end): edges useful only at iter 0 (dr,ds<=2)
// word = s(19b) | rl(8b)<<19 | flag<<27.  Spill -> ovf list (edge ids).
// ---------------------------------------------------------------------------
__global__ __launch_bounds__(256) void bin_kernel(
                           const int* __restrict__ recv,
                           const int* __restrict__ send,
                           const uint32_t* __restrict__ depth2,
                           uint32_t* __restrict__ cntF,
                           uint32_t* __restrict__ cntB,
                           uint32_t* __restrict__ ovfc,
                           uint32_t* __restrict__ ovf,
                           uint32_t* __restrict__ bins,
                           int ne)
{
    __shared__ uint32_t lh[NBMAX];     // packed counts: front lo16, back hi16
    __shared__ uint32_t wgF[NBMAX];
    __shared__ uint32_t wgB[NBMAX];
    const int t = threadIdx.x;
    for (int i = t; i < NBMAX; i += 256) lh[i] = 0;
    __syncthreads();

    const int base = blockIdx.x * EPW;

    // phase 1: stream edge endpoints
    int rA[KPT], sA[KPT];
    #pragma unroll
    for (int k = 0; k < KPT; ++k) {
        int e = base + k * 256 + t;
        if (e < ne) { rA[k] = recv[e]; sA[k] = send[e]; }
        else        { rA[k] = -1;      sA[k] = 0;       }
    }
    // phase 2: depth2 gathers (125 KB table, cache-hot), issued back-to-back
    int drA[KPT], dsA[KPT];
    #pragma unroll
    for (int k = 0; k < KPT; ++k) {
        if (rA[k] >= 0) { drA[k] = d2get(depth2, rA[k]); dsA[k] = d2get(depth2, sA[k]); }
        else            { drA[k] = 3;                    dsA[k] = 3;                    }
    }
    // phase 3: local histogram
    uint32_t fl = 0;                   // 2 bits/edge: bit0 keep, bit1 front
    #pragma unroll
    for (int k = 0; k < KPT; ++k) {
        if (rA[k] >= 0 && drA[k] <= 2 && dsA[k] <= 2) {
            bool f1 = (drA[k] <= 1) && (dsA[k] <= 1);
            fl |= (f1 ? 3u : 1u) << (2 * k);
            atomicAdd(&lh[rA[k] >> BKT_LOG], f1 ? 1u : 0x10000u);
        }
    }
    __syncthreads();

    for (int i = t; i < NBMAX; i += 256) {
        uint32_t v = lh[i];
        if (v) {
            uint32_t f = v & 0xffffu, kb = v >> 16;
            if (f)  wgF[i] = atomicAdd(&cntF[i], f);
            if (kb) wgB[i] = atomicAdd(&cntB[i], kb);
        }
    }
    __syncthreads();
    for (int i = t; i < NBMAX; i += 256) lh[i] = 0;   // reuse as local cursors
    __syncthreads();

    #pragma unroll
    for (int k = 0; k < KPT; ++k) {
        if ((fl >> (2 * k)) & 1u) {
            int r = rA[k], s = sA[k];
            int b = r >> BKT_LOG;
            bool f1 = (fl >> (2 * k)) & 2u;
            uint32_t w = (uint32_t)s | ((uint32_t)(r & (BKT - 1)) << 19)
                       | (f1 ? (1u << 27) : 0u);
            if (f1) {
                uint32_t o = atomicAdd(&lh[b], 1u) & 0xffffu;
                uint32_t pos = wgF[b] + o;
                if (pos < CAPF) bins[(size_t)b * CAPB + pos] = w;
                else { uint32_t oi = atomicAdd(ovfc, 1u);
                       if (oi < OVFCAP) ovf[oi] = (uint32_t)(base + k * 256 + t); }
            } else {
                uint32_t o = atomicAdd(&lh[b], 0x10000u) >> 16;
                uint32_t pos = wgB[b] + o;
                if (pos < CAPK) bins[(size_t)b * CAPB + (CAPB - 1) - pos] = w;
                else { uint32_t oi = atomicAdd(ovfc, 1u);
                       if (oi < OVFCAP) ovf[oi] = (uint32_t)(base + k * 256 + t); }
            }
        }
    }
}

// ---------------------------------------------------------------------------
// scatter: one WG per 256-node bucket; direct bins read (no sort);
// fp16 h-gather (32-B records); fp32 LDS accumulate; K=4 batching.
// LDS = 10 KB -> 8 WGs/CU (wave-limited max occupancy).
// ---------------------------------------------------------------------------
template<int ITER>
__global__ __launch_bounds__(256) void scat_kernel(
                            const uint32_t* __restrict__ bins,
                            const uint32_t* __restrict__ cntF,
                            const uint32_t* __restrict__ cntB,
                            const uint16_t* __restrict__ h16,  // stride 16 halfs
                            float* __restrict__ x,             // stride 10
                            int n)
{
    __shared__ float xl[BKT * DIM];      // 10240 B
    const int t = threadIdx.x;
    const int b = blockIdx.x;
    const int n0 = b << BKT_LOG;
    const int nb = min(BKT, n - n0);

    for (int i = t; i < BKT * DIM; i += 256) xl[i] = 0.0f;
    __syncthreads();

    const size_t base = (size_t)b * CAPB;
    const int fc = (int)min(cntF[b], (uint32_t)CAPF);
    int tot = fc, boff = 0;
    if (ITER == 0) {
        int bc = (int)min(cntB[b], (uint32_t)CAPK);
        tot = fc + bc;
        boff = CAPB - bc - fc;           // maps i in [fc,tot) -> end segment
    }

    for (int i0 = t; i0 < tot; i0 += 256 * 4) {
        uint32_t w[4];
        bool v[4];
        #pragma unroll
        for (int k = 0; k < 4; ++k) {
            int i = i0 + k * 256;
            v[k] = (i < tot);
            if (v[k]) {
                size_t idx = base + (size_t)((ITER == 0 && i >= fc) ? (i + boff) : i);
                w[k] = bins[idx];
            }
        }
        uint4 q[4]; uint32_t e8[4];
        #pragma unroll
        for (int k = 0; k < 4; ++k) {
            if (v[k]) {
                size_t s = (size_t)(w[k] & 0x7FFFFu);
                q[k]  = *reinterpret_cast<const uint4*>(h16 + s * 16);
                e8[k] = *reinterpret_cast<const uint32_t*>(h16 + s * 16 + 8);
            }
        }
        #pragma unroll
        for (int k = 0; k < 4; ++k) {
            if (v[k]) {
                float2 f0 = cvt2(q[k].x), f1 = cvt2(q[k].y);
                float2 f2 = cvt2(q[k].z), f3 = cvt2(q[k].w);
                float2 f4 = cvt2(e8[k]);
                uint32_t rl = (w[k] >> 19) & (BKT - 1);
                float* xr = xl + rl * DIM;
                atomicAdd(xr + 0, f0.x); atomicAdd(xr + 1, f0.y);
                atomicAdd(xr + 2, f1.x); atomicAdd(xr + 3, f1.y);
                atomicAdd(xr + 4, f2.x); atomicAdd(xr + 5, f2.y);
                atomicAdd(xr + 6, f3.x); atomicAdd(xr + 7, f3.y);
                atomicAdd(xr + 8, f4.x); atomicAdd(xr + 9, f4.y);
            }
        }
    }
    __syncthreads();

    float* xo = x + (size_t)n0 * DIM;
    for (int i = t; i < nb * DIM; i += 256) xo[i] = xl[i];
}

// ---------------------------------------------------------------------------
// spilled edges: exact fp32 path via global HW atomics (count ~O(100))
// ---------------------------------------------------------------------------
__global__ void ovf_apply_kernel(const uint32_t* __restrict__ ovfc,
                                 const uint32_t* __restrict__ ovf,
                                 const int* __restrict__ recv,
                                 const int* __restrict__ send,
                                 const int* __restrict__ depth,
                                 const float* __restrict__ h32,  // stride 10
                                 float* __restrict__ x,          // stride 10
                                 int iter)
{
    const uint32_t cnt = min(*ovfc, (uint32_t)OVFCAP);
    for (uint32_t i = blockIdx.x * blockDim.x + threadIdx.x; i < cnt;
         i += gridDim.x * blockDim.x) {
        int e = (int)ovf[i];
        int r = recv[e], s = send[e];
        if (iter == 1 && (depth[r] > 1 || depth[s] > 1)) continue;
        const float* hr = h32 + (size_t)s * DIM;
        float* xr = x + (size_t)r * DIM;
        #pragma unroll
        for (int c = 0; c < DIM; ++c) unsafeAtomicAdd(xr + c, hr[c]);
    }
}

// ---------------------------------------------------------------------------
// init: h32[node] = (depth<=2)? h_in[node] : 0  (stride 10)
//       h16[node] = half(h32[node])             (stride 16 halfs, pads 0)
// ---------------------------------------------------------------------------
__global__ void init_mask_kernel(const float* __restrict__ hsrc,
                                 float* __restrict__ h32,
                                 uint16_t* __restrict__ h16,
                                 const int* __restrict__ depth,
                                 int n)
{
    __shared__ float sh[NTILE * 11];
    const int t = threadIdx.x;
    const int base = blockIdx.x * NTILE;

    const long gbase = (long)base * DIM;
    const long glim  = (long)n * DIM;
    for (int idx = t; idx < NTILE * DIM; idx += NTILE) {
        long g = gbase + idx;
        float v = (g < glim) ? hsrc[g] : 0.0f;
        sh[(idx / DIM) * 11 + (idx % DIM)] = v;
    }
    __syncthreads();

    const int node = base + t;
    if (node < n && depth[node] > 2) {
        #pragma unroll
        for (int c = 0; c < DIM; ++c) sh[t * 11 + c] = 0.0f;
    }
    __syncthreads();

    // write h32 (stride 10, coalesced)
    for (int idx = t; idx < NTILE * DIM; idx += NTILE) {
        long g = gbase + idx;
        if (g < glim) h32[g] = sh[(idx / DIM) * 11 + (idx % DIM)];
    }
    // write h16 (8 uints per node, coalesced); skipped when not provided
    if (h16 != nullptr) {
        uint32_t* o16 = reinterpret_cast<uint32_t*>(h16);
        const long o16base = (long)base * 8;
        const long o16lim  = (long)n * 8;
        for (int idx = t; idx < NTILE * 8; idx += NTILE) {
            long g = o16base + idx;
            if (g < o16lim) {
                int nl = idx / 8, c2 = idx % 8;
                uint32_t w = 0;
                if (c2 < 5) {
                    __half2 hh = __floats2half2_rn(sh[nl * 11 + 2 * c2],
                                                   sh[nl * 11 + 2 * c2 + 1]);
                    w = *reinterpret_cast<uint32_t*>(&hh);
                }
                o16[g] = w;
            }
        }
    }
}

// ---------------------------------------------------------------------------
// GRU update, LDS tile-staged; x,h stride 10; out32 stride 10 (+optional h16)
// ---------------------------------------------------------------------------
template<int NEXTMASK, int WRITE16>
__global__ void gru_kernel(const float* __restrict__ x,
                           const float* __restrict__ h,
                           float* __restrict__ out32,
                           uint16_t* __restrict__ out16,
                           const int* __restrict__ depth, int iter, int n,
                           const float* __restrict__ Wz, const float* __restrict__ bz,
                           const float* __restrict__ Uz, const float* __restrict__ buz,
                           const float* __restrict__ Wr, const float* __restrict__ br,
                           const float* __restrict__ Ur, const float* __restrict__ bur,
                           const float* __restrict__ Wh, const float* __restrict__ bh,
                           const float* __restrict__ Uh, const float* __restrict__ buh)
{
    __shared__ float sx[NTILE * 17];
    __shared__ float shh[NTILE * 17];
    __shared__ float sW[6][100];
    __shared__ float sb[3][10];

    const int t = threadIdx.x;
    if (t < 100) {
        sW[0][t] = Wz[t]; sW[1][t] = Uz[t];
        sW[2][t] = Wr[t]; sW[3][t] = Ur[t];
        sW[4][t] = Wh[t]; sW[5][t] = Uh[t];
    }
    if (t < 10) {
        sb[0][t] = bz[t] + buz[t];
        sb[1][t] = br[t] + bur[t];
        sb[2][t] = bh[t] + buh[t];
    }

    const int base = blockIdx.x * NTILE;

    {   // stage x tile (stride 10, float4)
        const int tile4 = NTILE * DIM / 4;
        const long g4base = (long)base * DIM / 4;
        const long g4lim  = (long)n * DIM / 4;
        const float4* xg = reinterpret_cast<const float4*>(x);
        for (int i4 = t; i4 < tile4; i4 += NTILE) {
            long g = g4base + i4;
            if (g < g4lim) {
                float4 v = xg[g];
                float vv[4] = {v.x, v.y, v.z, v.w};
                int f = i4 * 4;
                int nl = f / DIM, c = f % DIM;
                #pragma unroll
                for (int k = 0; k < 4; ++k) {
                    sx[nl * 17 + c] = vv[k];
                    if (++c == DIM) { c = 0; ++nl; }
                }
            }
        }
    }
    {   // stage h tile (stride 10, float4)
        const int tile4 = NTILE * DIM / 4;
        const long g4base = (long)base * DIM / 4;
        const long g4lim  = (long)n * DIM / 4;
        const float4* hg = reinterpret_cast<const float4*>(h);
        for (int i4 = t; i4 < tile4; i4 += NTILE) {
            long g = g4base + i4;
            if (g < g4lim) {
                float4 v = hg[g];
                float vv[4] = {v.x, v.y, v.z, v.w};
                int f = i4 * 4;
                int nl = f / DIM, c = f % DIM;
                #pragma unroll
                for (int k = 0; k < 4; ++k) {
                    shh[nl * 17 + c] = vv[k];
                    if (++c == DIM) { c = 0; ++nl; }
                }
            }
        }
    }
    __syncthreads();

    const int node = base + t;
    const bool valid = node < n;
    const int dep = valid ? depth[node] : 99;
    const bool active = valid && (dep + iter <= 2);

    float xv[DIM], hv[DIM], outv[DIM];
    #pragma unroll
    for (int j = 0; j < DIM; ++j) {
        xv[j] = sx[t * 17 + j];
        hv[j] = shh[t * 17 + j];
    }

    if (active) {
        float zz[DIM], rr[DIM];
        #pragma unroll
        for (int i = 0; i < DIM; ++i) {
            float az = sb[0][i];
            float ar = sb[1][i];
            #pragma unroll
            for (int j = 0; j < DIM; ++j) {
                az = fmaf(xv[j], sW[0][i * DIM + j], az);
                az = fmaf(hv[j], sW[1][i * DIM + j], az);
                ar = fmaf(xv[j], sW[2][i * DIM + j], ar);
                ar = fmaf(hv[j], sW[3][i * DIM + j], ar);
            }
            zz[i] = 1.0f / (1.0f + __expf(-az));
            rr[i] = 1.0f / (1.0f + __expf(-ar));
        }
        float rh[DIM];
        #pragma unroll
        for (int j = 0; j < DIM; ++j) rh[j] = rr[j] * hv[j];
        #pragma unroll
        for (int i = 0; i < DIM; ++i) {
            float ah = sb[2][i];
            #pragma unroll
            for (int j = 0; j < DIM; ++j) {
                ah = fmaf(xv[j], sW[4][i * DIM + j], ah);
                ah = fmaf(rh[j], sW[5][i * DIM + j], ah);
            }
            float th = tanhf(ah);
            outv[i] = zz[i] * hv[i] + (1.0f - zz[i]) * th;
        }
    } else {
        #pragma unroll
        for (int i = 0; i < DIM; ++i) outv[i] = hv[i];   // inactive: h already 0
    }

    if (NEXTMASK) {
        const bool keep = valid && (dep + iter + 1 <= 2);
        if (!keep) {
            #pragma unroll
            for (int i = 0; i < DIM; ++i) outv[i] = 0.0f;
        }
    }

    __syncthreads();
    #pragma unroll
    for (int i = 0; i < DIM; ++i) sx[t * 17 + i] = outv[i];
    __syncthreads();

    // flush out32 (stride 10)
    const long obase = (long)base * DIM;
    const long olim  = (long)n * DIM;
    for (int idx = t; idx < NTILE * DIM; idx += NTILE) {
        long g = obase + idx;
        if (g < olim) out32[g] = sx[(idx / DIM) * 17 + (idx % DIM)];
    }
    // flush out16 (stride 16 halfs)
    if (WRITE16) {
        uint32_t* o16 = reinterpret_cast<uint32_t*>(out16);
        const long o16base = (long)base * 8;
        const long o16lim  = (long)n * 8;
        for (int idx = t; idx < NTILE * 8; idx += NTILE) {
            long g = o16base + idx;
            if (g < o16lim) {
                int nl = idx / 8, c2 = idx % 8;
                uint32_t w = 0;
                if (c2 < 5) {
                    __half2 hh = __floats2half2_rn(sx[nl * 17 + 2 * c2],
                                                   sx[nl * 17 + 2 * c2 + 1]);
                    w = *reinterpret_cast<uint32_t*>(&hh);
                }
                o16[g] = w;
            }
        }
    }
}

// ---------------------------------------------------------------------------
// fallback simple atomic scatter (only if ws too small / n too large)
// ---------------------------------------------------------------------------
__global__ void simple_scatter_kernel(const int* __restrict__ recv,
                                      const int* __restrict__ send,
                                      const float* __restrict__ hm,  // stride 10
                                      float* __restrict__ x,         // stride 10
                                      int ne)
{
    const int tid = blockIdx.x * blockDim.x + threadIdx.x;
    const int e = tid / DIM;
    if (e >= ne) return;
    const int c = tid - e * DIM;
    const int s = send[e];
    const float v = hm[(size_t)s * DIM + c];
    if (v != 0.0f) {
        const int r = recv[e];
        unsafeAtomicAdd(x + (size_t)r * DIM + c, v);
    }
}

__global__ void zero_buf_kernel(float4* __restrict__ p, int tot4) {
    int i = blockIdx.x * blockDim.x + threadIdx.x;
    if (i < tot4) p[i] = make_float4(0.0f, 0.0f, 0.0f, 0.0f);
}

extern "C" void kernel_launch(void* const* d_in, const int* in_sizes, int n_in,
                              void* d_out, int out_size, void* d_ws, size_t ws_size,
                              hipStream_t stream) {
    const float* h_in  = (const float*)d_in[0];
    const int*   edges = (const int*)d_in[1];
    const int*   depth = (const int*)d_in[2];
    const float* Wz  = (const float*)d_in[3];
    const float* bz  = (const float*)d_in[4];
    const float* Uz  = (const float*)d_in[5];
    const float* buz = (const float*)d_in[6];
    const float* Wr  = (const float*)d_in[7];
    const float* br  = (const float*)d_in[8];
    const float* Ur  = (const float*)d_in[9];
    const float* bur = (const float*)d_in[10];
    const float* Wh  = (const float*)d_in[11];
    const float* bh  = (const float*)d_in[12];
    const float* Uh  = (const float*)d_in[13];
    const float* buh = (const float*)d_in[14];

    const int n  = in_sizes[0] / DIM;       // 500,000
    const int ne = in_sizes[1] / 2;         // 8,000,000
    const int* recv = edges;
    const int* send = edges + ne;

    const int NB = (n + BKT - 1) >> BKT_LOG;
    const size_t meta_words = 2 * NBMAX + 8 + OVFCAP + D2WORDS;
    const size_t need = (size_t)n * DIM * sizeof(float) * 2      // x + h32
                      + (size_t)n * 16 * sizeof(uint16_t)        // h16
                      + meta_words * sizeof(uint32_t);

    const int BLK = 256;
    const int node_blocks = (n + NTILE - 1) / NTILE;

    if (ws_size >= need && n <= (1 << 19) && NB <= NBMAX &&
        (size_t)NB * CAPB <= (size_t)out_size) {
        float*    x    = (float*)d_ws;                         // [n*10]
        float*    h32  = (float*)d_ws + (size_t)n * DIM;       // [n*10]
        uint16_t* h16  = (uint16_t*)(h32 + (size_t)n * DIM);   // [n*16]
        uint32_t* meta = (uint32_t*)(h16 + (size_t)n * 16);
        uint32_t* cntF   = meta;                      // NBMAX
        uint32_t* cntB   = meta + NBMAX;              // NBMAX
        uint32_t* ovfc   = meta + 2 * NBMAX;          // 8 (1 used)
        uint32_t* ovf    = meta + 2 * NBMAX + 8;      // OVFCAP
        uint32_t* depth2 = meta + 2 * NBMAX + 8 + OVFCAP;  // D2WORDS
        uint32_t* bins = (uint32_t*)d_out;

        const int meta_tot = 2 * NBMAX + 1;
        const int bin_blocks = (ne + EPW - 1) / EPW;
        const int pack_blocks = (n + 4095) / 4096;

        meta_zero_kernel<<<(meta_tot + BLK - 1) / BLK, BLK, 0, stream>>>(meta, meta_tot);
        pack_depth_kernel<<<pack_blocks, BLK, 0, stream>>>(depth, depth2, n);
        bin_kernel<<<bin_blocks, BLK, 0, stream>>>(recv, send, depth2,
                                                   cntF, cntB, ovfc, ovf, bins, ne);
        init_mask_kernel<<<node_blocks, NTILE, 0, stream>>>(h_in, h32, h16, depth, n);

        // ---- iteration 0 (active: depth<=2) ----
        scat_kernel<0><<<NB, BLK, 0, stream>>>(bins, cntF, cntB, h16, x, n);
        ovf_apply_kernel<<<16, BLK, 0, stream>>>(ovfc, ovf, recv, send, depth, h32, x, 0);
        gru_kernel<1, 1><<<node_blocks, NTILE, 0, stream>>>(x, h32, h32, h16, depth, 0, n,
            Wz, bz, Uz, buz, Wr, br, Ur, bur, Wh, bh, Uh, buh);

        // ---- iteration 1 (active: depth<=1) ----
        scat_kernel<1><<<NB, BLK, 0, stream>>>(bins, cntF, cntB, h16, x, n);
        ovf_apply_kernel<<<16, BLK, 0, stream>>>(ovfc, ovf, recv, send, depth, h32, x, 1);
        gru_kernel<0, 0><<<node_blocks, NTILE, 0, stream>>>(x, h32, (float*)d_out, nullptr, depth, 1, n,
            Wz, bz, Uz, buz, Wr, br, Ur, bur, Wh, bh, Uh, buh);
    } else {
        // fallback: unpadded atomic path, h in d_out (h16 disabled)
        float* x    = (float*)d_ws;
        float* hbuf = (float*)d_out;
        const int nwork = ne * DIM;
        const int edge_blocks = (nwork + BLK - 1) / BLK;
        const int x_tot4 = (n * DIM) / 4;
        const int xz_blocks = (x_tot4 + BLK - 1) / BLK;

        init_mask_kernel<<<node_blocks, NTILE, 0, stream>>>(h_in, hbuf, nullptr, depth, n);
        zero_buf_kernel<<<xz_blocks, BLK, 0, stream>>>((float4*)x, x_tot4);
        simple_scatter_kernel<<<edge_blocks, BLK, 0, stream>>>(recv, send, hbuf, x, ne);
        gru_kernel<1, 0><<<node_blocks, NTILE, 0, stream>>>(x, hbuf, hbuf, nullptr, depth, 0, n,
            Wz, bz, Uz, buz, Wr, br, Ur, bur, Wh, bh, Uh, buh);
        zero_buf_kernel<<<xz_blocks, BLK, 0, stream>>>((float4*)x, x_tot4);
        simple_scatter_kernel<<<edge_blocks, BLK, 0, stream>>>(recv, send, hbuf, x, ne);
        gru_kernel<0, 0><<<node_blocks, NTILE, 0, stream>>>(x, hbuf, hbuf, nullptr, depth, 1, n,
            Wz, bz, Uz, buz, Wr, br, Ur, bur, Wh, bh, Uh, buh);
    }
}

// Round 12
// 646.677 us; speedup vs baseline: 1.5100x; 1.3668x over previous
//
#include <hip/hip_runtime.h>
#include <hip/hip_fp16.h>
#include <math.h>
#include <stdint.h>

#define DIM 10
#define NTILE 256
#define BKT_LOG 8
#define BKT 256                   // nodes per bucket == threads per WG
#define NBMAX 2048
#define EPW 2048                  // edges per WG in binning
#define KPT (EPW / 256)
#define CAPB 2816                 // slots per bucket
#define CAPF 1280                 // front region (mean 1024 + ~8 sigma)
#define CAPK (CAPB - CAPF)       // back region  (mean 1280 + ~7 sigma)
#define OVFCAP 32768
#define D2WORDS 32768

// meta (u32): cntF[NBMAX] | cntB[NBMAX] | ovfc[8] | ovf[OVFCAP] | depth2[D2WORDS]
// ws: h16a[n*16 u16] | h16b[n*16 u16] | bins[NB*CAPB u32] | meta

__device__ __forceinline__ float2 cvt2(uint32_t u) {
    __half2 hh = *reinterpret_cast<__half2*>(&u);
    return __half22float2(hh);
}

__device__ __forceinline__ int d2get(const uint32_t* __restrict__ depth2, int node) {
    uint32_t w = depth2[(uint32_t)node >> 4];
    return (int)((w >> ((node & 15) * 2)) & 3u);
}

// ---------------------------------------------------------------------------
// prep: blocks [0,pack_blocks) pack depth into 2-bit table;
//       blocks [pack_blocks, ...) zero the counters (cntF,cntB,ovfc[0]).
// ---------------------------------------------------------------------------
__global__ void prep_kernel(const int* __restrict__ depth,
                            uint32_t* __restrict__ depth2,
                            uint32_t* __restrict__ cnts,   // meta base
                            int n, int pack_blocks, int cnt_tot)
{
    __shared__ int sd[4096];
    const int t = threadIdx.x;
    const int bid = blockIdx.x;
    if (bid < pack_blocks) {
        const int base = bid * 4096;
        for (int i = t; i < 4096; i += 256) {
            int g = base + i;
            sd[i] = (g < n) ? depth[g] : 3;
        }
        __syncthreads();
        const int wbase = base >> 4;
        int wb = wbase + t;
        if (wb * 16 < n) {
            uint32_t v = 0;
            #pragma unroll
            for (int j = 0; j < 16; ++j)
                v |= ((uint32_t)(sd[t * 16 + j] & 3)) << (2 * j);
            depth2[wb] = v;
        }
    } else {
        int i = (bid - pack_blocks) * 256 + t;
        if (i < cnt_tot) cnts[i] = 0;
    }
}

// ---------------------------------------------------------------------------
// binit: blocks [0,bin_blocks) do edge binning (round-11 structure);
//        blocks [bin_blocks, +node_blocks) do init: h16a = fp16(mask(h_in)).
// LDS union: bin needs 3*NBMAX u32 (24KB); init aliases first 11KB as float.
// ---------------------------------------------------------------------------
__global__ __launch_bounds__(256) void binit_kernel(
                           const int* __restrict__ recv,
                           const int* __restrict__ send,
                           const uint32_t* __restrict__ depth2,
                           const int* __restrict__ depth,
                           const float* __restrict__ h_in,
                           uint16_t* __restrict__ h16a,
                           uint32_t* __restrict__ cntF,
                           uint32_t* __restrict__ cntB,
                           uint32_t* __restrict__ ovfc,
                           uint32_t* __restrict__ ovf,
                           uint32_t* __restrict__ bins,
                           int ne, int n, int bin_blocks)
{
    __shared__ uint32_t u[3 * NBMAX];    // 24 KB
    const int t = threadIdx.x;
    const int bid = blockIdx.x;

    if (bid < bin_blocks) {
        uint32_t* lh  = u;
        uint32_t* wgF = u + NBMAX;
        uint32_t* wgB = u + 2 * NBMAX;
        for (int i = t; i < NBMAX; i += 256) lh[i] = 0;
        __syncthreads();

        const int base = bid * EPW;
        int rA[KPT], sA[KPT];
        #pragma unroll
        for (int k = 0; k < KPT; ++k) {
            int e = base + k * 256 + t;
            if (e < ne) { rA[k] = recv[e]; sA[k] = send[e]; }
            else        { rA[k] = -1;      sA[k] = 0;       }
        }
        int drA[KPT], dsA[KPT];
        #pragma unroll
        for (int k = 0; k < KPT; ++k) {
            if (rA[k] >= 0) { drA[k] = d2get(depth2, rA[k]); dsA[k] = d2get(depth2, sA[k]); }
            else            { drA[k] = 3;                    dsA[k] = 3;                    }
        }
        uint32_t fl = 0;
        #pragma unroll
        for (int k = 0; k < KPT; ++k) {
            if (rA[k] >= 0 && drA[k] <= 2 && dsA[k] <= 2) {
                bool f1 = (drA[k] <= 1) && (dsA[k] <= 1);
                fl |= (f1 ? 3u : 1u) << (2 * k);
                atomicAdd(&lh[rA[k] >> BKT_LOG], f1 ? 1u : 0x10000u);
            }
        }
        __syncthreads();

        for (int i = t; i < NBMAX; i += 256) {
            uint32_t v = lh[i];
            if (v) {
                uint32_t f = v & 0xffffu, kb = v >> 16;
                if (f)  wgF[i] = atomicAdd(&cntF[i], f);
                if (kb) wgB[i] = atomicAdd(&cntB[i], kb);
            }
        }
        __syncthreads();
        for (int i = t; i < NBMAX; i += 256) lh[i] = 0;   // reuse as cursors
        __syncthreads();

        #pragma unroll
        for (int k = 0; k < KPT; ++k) {
            if ((fl >> (2 * k)) & 1u) {
                int r = rA[k], s = sA[k];
                int b = r >> BKT_LOG;
                bool f1 = (fl >> (2 * k)) & 2u;
                uint32_t w = (uint32_t)s | ((uint32_t)(r & (BKT - 1)) << 19)
                           | (f1 ? (1u << 27) : 0u);
                if (f1) {
                    uint32_t o = atomicAdd(&lh[b], 1u) & 0xffffu;
                    uint32_t pos = wgF[b] + o;
                    if (pos < CAPF) bins[(size_t)b * CAPB + pos] = w;
                    else { uint32_t oi = atomicAdd(ovfc, 1u);
                           if (oi < OVFCAP) ovf[oi] = (uint32_t)(base + k * 256 + t); }
                } else {
                    uint32_t o = atomicAdd(&lh[b], 0x10000u) >> 16;
                    uint32_t pos = wgB[b] + o;
                    if (pos < CAPK) bins[(size_t)b * CAPB + (CAPB - 1) - pos] = w;
                    else { uint32_t oi = atomicAdd(ovfc, 1u);
                           if (oi < OVFCAP) ovf[oi] = (uint32_t)(base + k * 256 + t); }
                }
            }
        }
    } else {
        // ---- init: h16a[node] = fp16( (depth<=2) ? h_in[node] : 0 ), pads 0
        float* sh = reinterpret_cast<float*>(u);   // 11 KB of the union
        const int tile = bid - bin_blocks;
        const int base = tile * NTILE;

        const long gbase = (long)base * DIM;
        const long glim  = (long)n * DIM;
        for (int idx = t; idx < NTILE * DIM; idx += NTILE) {
            long g = gbase + idx;
            float v = (g < glim) ? h_in[g] : 0.0f;
            sh[(idx / DIM) * 11 + (idx % DIM)] = v;
        }
        __syncthreads();

        const int node = base + t;
        if (node < n && depth[node] > 2) {
            #pragma unroll
            for (int c = 0; c < DIM; ++c) sh[t * 11 + c] = 0.0f;
        }
        __syncthreads();

        uint32_t* o16 = reinterpret_cast<uint32_t*>(h16a);
        const long o16base = (long)base * 8;
        const long o16lim  = (long)n * 8;
        for (int idx = t; idx < NTILE * 8; idx += NTILE) {
            long g = o16base + idx;
            if (g < o16lim) {
                int nl = idx / 8, c2 = idx % 8;
                uint32_t w = 0;
                if (c2 < 5) {
                    __half2 hh = __floats2half2_rn(sh[nl * 11 + 2 * c2],
                                                   sh[nl * 11 + 2 * c2 + 1]);
                    w = *reinterpret_cast<uint32_t*>(&hh);
                }
                o16[g] = w;
            }
        }
    }
}

// ---------------------------------------------------------------------------
// fused scatter + GRU: one WG per 256-node bucket.
//   phase 1: gather h16 rows of this bucket's edges, accumulate x in LDS
//   phase 2: apply rare overflow edges for this bucket
//   phase 3: thread t = node n0+t computes GRU(x, h) and writes the result:
//            ITER==0 -> hnext (fp16, 32B records, masked for iter 1)
//            ITER==1 -> out32 (fp32, stride 10) == d_out
// ---------------------------------------------------------------------------
template<int ITER>
__global__ __launch_bounds__(256) void scatgru_kernel(
                            const uint32_t* __restrict__ bins,
                            const uint32_t* __restrict__ cntF,
                            const uint32_t* __restrict__ cntB,
                            const uint32_t* __restrict__ ovfc,
                            const uint32_t* __restrict__ ovf,
                            const int* __restrict__ recv,
                            const int* __restrict__ send,
                            const int* __restrict__ depth,
                            const uint16_t* __restrict__ hcur,  // stride 16 halfs
                            uint16_t* __restrict__ hnext,       // ITER==0 out
                            float* __restrict__ out32,          // ITER==1 out
                            int n,
                            const float* __restrict__ Wz, const float* __restrict__ bz,
                            const float* __restrict__ Uz, const float* __restrict__ buz,
                            const float* __restrict__ Wr, const float* __restrict__ br,
                            const float* __restrict__ Ur, const float* __restrict__ bur,
                            const float* __restrict__ Wh, const float* __restrict__ bh,
                            const float* __restrict__ Uh, const float* __restrict__ buh)
{
    __shared__ float xl[BKT * DIM];      // 10240 B
    __shared__ float sW[6][100];
    __shared__ float sb[3][10];

    const int t = threadIdx.x;
    if (t < 100) {
        sW[0][t] = Wz[t]; sW[1][t] = Uz[t];
        sW[2][t] = Wr[t]; sW[3][t] = Ur[t];
        sW[4][t] = Wh[t]; sW[5][t] = Uh[t];
    }
    if (t < 10) {
        sb[0][t] = bz[t] + buz[t];
        sb[1][t] = br[t] + bur[t];
        sb[2][t] = bh[t] + buh[t];
    }
    for (int i = t; i < BKT * DIM; i += 256) xl[i] = 0.0f;
    __syncthreads();

    const int b = blockIdx.x;
    const int n0 = b << BKT_LOG;
    const int nb = min(BKT, n - n0);

    const size_t base = (size_t)b * CAPB;
    const int fc = (int)min(cntF[b], (uint32_t)CAPF);
    int tot = fc, boff = 0;
    if (ITER == 0) {
        int bc = (int)min(cntB[b], (uint32_t)CAPK);
        tot = fc + bc;
        boff = CAPB - bc - fc;
    }

    // phase 1: gather + LDS accumulate (K=4 batching)
    for (int i0 = t; i0 < tot; i0 += 256 * 4) {
        uint32_t w[4];
        bool v[4];
        #pragma unroll
        for (int k = 0; k < 4; ++k) {
            int i = i0 + k * 256;
            v[k] = (i < tot);
            if (v[k]) {
                size_t idx = base + (size_t)((ITER == 0 && i >= fc) ? (i + boff) : i);
                w[k] = bins[idx];
            }
        }
        uint4 q[4]; uint32_t e8[4];
        #pragma unroll
        for (int k = 0; k < 4; ++k) {
            if (v[k]) {
                size_t s = (size_t)(w[k] & 0x7FFFFu);
                q[k]  = *reinterpret_cast<const uint4*>(hcur + s * 16);
                e8[k] = *reinterpret_cast<const uint32_t*>(hcur + s * 16 + 8);
            }
        }
        #pragma unroll
        for (int k = 0; k < 4; ++k) {
            if (v[k]) {
                float2 f0 = cvt2(q[k].x), f1 = cvt2(q[k].y);
                float2 f2 = cvt2(q[k].z), f3 = cvt2(q[k].w);
                float2 f4 = cvt2(e8[k]);
                float* xr = xl + ((w[k] >> 19) & (BKT - 1)) * DIM;
                atomicAdd(xr + 0, f0.x); atomicAdd(xr + 1, f0.y);
                atomicAdd(xr + 2, f1.x); atomicAdd(xr + 3, f1.y);
                atomicAdd(xr + 4, f2.x); atomicAdd(xr + 5, f2.y);
                atomicAdd(xr + 6, f3.x); atomicAdd(xr + 7, f3.y);
                atomicAdd(xr + 8, f4.x); atomicAdd(xr + 9, f4.y);
            }
        }
    }

    // phase 2: rare overflow edges for this bucket
    {
        const uint32_t cnt = min(*ovfc, (uint32_t)OVFCAP);
        for (uint32_t i = t; i < cnt; i += 256) {
            int e = (int)ovf[i];
            int r = recv[e];
            if ((r >> BKT_LOG) != b) continue;
            int s = send[e];
            if (ITER == 1 && (depth[r] > 1 || depth[s] > 1)) continue;
            uint4 q = *reinterpret_cast<const uint4*>(hcur + (size_t)s * 16);
            uint32_t e8v = *reinterpret_cast<const uint32_t*>(hcur + (size_t)s * 16 + 8);
            float2 f0 = cvt2(q.x), f1 = cvt2(q.y), f2 = cvt2(q.z), f3 = cvt2(q.w);
            float2 f4 = cvt2(e8v);
            float* xr = xl + (r & (BKT - 1)) * DIM;
            atomicAdd(xr + 0, f0.x); atomicAdd(xr + 1, f0.y);
            atomicAdd(xr + 2, f1.x); atomicAdd(xr + 3, f1.y);
            atomicAdd(xr + 4, f2.x); atomicAdd(xr + 5, f2.y);
            atomicAdd(xr + 6, f3.x); atomicAdd(xr + 7, f3.y);
            atomicAdd(xr + 8, f4.x); atomicAdd(xr + 9, f4.y);
        }
    }
    __syncthreads();

    // phase 3: GRU for node n0+t
    if (t < nb) {
        const int node = n0 + t;
        const int dep = depth[node];
        const bool active = (dep + ITER) <= 2;

        float hv[DIM], xv[DIM], outv[DIM];
        {
            const uint16_t* hp = hcur + (size_t)node * 16;
            uint4 q = *reinterpret_cast<const uint4*>(hp);
            uint32_t e8v = *reinterpret_cast<const uint32_t*>(hp + 8);
            float2 f0 = cvt2(q.x), f1 = cvt2(q.y), f2 = cvt2(q.z), f3 = cvt2(q.w);
            float2 f4 = cvt2(e8v);
            hv[0] = f0.x; hv[1] = f0.y; hv[2] = f1.x; hv[3] = f1.y;
            hv[4] = f2.x; hv[5] = f2.y; hv[6] = f3.x; hv[7] = f3.y;
            hv[8] = f4.x; hv[9] = f4.y;
        }
        #pragma unroll
        for (int j = 0; j < DIM; ++j) xv[j] = xl[t * DIM + j];

        if (active) {
            float zz[DIM], rr[DIM];
            #pragma unroll
            for (int i = 0; i < DIM; ++i) {
                float az = sb[0][i];
                float ar = sb[1][i];
                #pragma unroll
                for (int j = 0; j < DIM; ++j) {
                    az = fmaf(xv[j], sW[0][i * DIM + j], az);
                    az = fmaf(hv[j], sW[1][i * DIM + j], az);
                    ar = fmaf(xv[j], sW[2][i * DIM + j], ar);
                    ar = fmaf(hv[j], sW[3][i * DIM + j], ar);
                }
                zz[i] = 1.0f / (1.0f + __expf(-az));
                rr[i] = 1.0f / (1.0f + __expf(-ar));
            }
            float rh[DIM];
            #pragma unroll
            for (int j = 0; j < DIM; ++j) rh[j] = rr[j] * hv[j];
            #pragma unroll
            for (int i = 0; i < DIM; ++i) {
                float ah = sb[2][i];
                #pragma unroll
                for (int j = 0; j < DIM; ++j) {
                    ah = fmaf(xv[j], sW[4][i * DIM + j], ah);
                    ah = fmaf(rh[j], sW[5][i * DIM + j], ah);
                }
                float th = tanhf(ah);
                outv[i] = zz[i] * hv[i] + (1.0f - zz[i]) * th;
            }
        } else {
            #pragma unroll
            for (int i = 0; i < DIM; ++i) outv[i] = hv[i];   // inactive: 0
        }

        if (ITER == 0) {
            // fold next iteration's mask: nodes with depth>1 are inactive at iter 1
            if (dep > 1) {
                #pragma unroll
                for (int i = 0; i < DIM; ++i) outv[i] = 0.0f;
            }
            __half2 h01 = __floats2half2_rn(outv[0], outv[1]);
            __half2 h23 = __floats2half2_rn(outv[2], outv[3]);
            __half2 h45 = __floats2half2_rn(outv[4], outv[5]);
            __half2 h67 = __floats2half2_rn(outv[6], outv[7]);
            __half2 h89 = __floats2half2_rn(outv[8], outv[9]);
            uint4 o0;
            o0.x = *reinterpret_cast<uint32_t*>(&h01);
            o0.y = *reinterpret_cast<uint32_t*>(&h23);
            o0.z = *reinterpret_cast<uint32_t*>(&h45);
            o0.w = *reinterpret_cast<uint32_t*>(&h67);
            uint4 o1;
            o1.x = *reinterpret_cast<uint32_t*>(&h89);
            o1.y = 0; o1.z = 0; o1.w = 0;
            *reinterpret_cast<uint4*>(hnext + (size_t)node * 16)     = o0;
            *reinterpret_cast<uint4*>(hnext + (size_t)node * 16 + 8) = o1;
        } else {
            float2* op = reinterpret_cast<float2*>(out32 + (size_t)node * DIM);
            op[0] = make_float2(outv[0], outv[1]);
            op[1] = make_float2(outv[2], outv[3]);
            op[2] = make_float2(outv[4], outv[5]);
            op[3] = make_float2(outv[6], outv[7]);
            op[4] = make_float2(outv[8], outv[9]);
        }
    }
}

// ---------------------------------------------------------------------------
// fallback path (ws too small / n too large): fp32 global-atomic pipeline
// ---------------------------------------------------------------------------
__global__ void init_mask32_kernel(const float* __restrict__ hsrc,
                                   float* __restrict__ hdst,
                                   const int* __restrict__ depth,
                                   int n)
{
    int node = blockIdx.x * blockDim.x + threadIdx.x;
    if (node >= n) return;
    bool act = depth[node] <= 2;
    const float* s = hsrc + (size_t)node * DIM;
    float* d = hdst + (size_t)node * DIM;
    #pragma unroll
    for (int c = 0; c < DIM; ++c) d[c] = act ? s[c] : 0.0f;
}

__global__ void simple_scatter_kernel(const int* __restrict__ recv,
                                      const int* __restrict__ send,
                                      const float* __restrict__ hm,
                                      float* __restrict__ x,
                                      int ne)
{
    const int tid = blockIdx.x * blockDim.x + threadIdx.x;
    const int e = tid / DIM;
    if (e >= ne) return;
    const int c = tid - e * DIM;
    const int s = send[e];
    const float v = hm[(size_t)s * DIM + c];
    if (v != 0.0f) {
        const int r = recv[e];
        unsafeAtomicAdd(x + (size_t)r * DIM + c, v);
    }
}

__global__ void zero_buf_kernel(float4* __restrict__ p, int tot4) {
    int i = blockIdx.x * blockDim.x + threadIdx.x;
    if (i < tot4) p[i] = make_float4(0.0f, 0.0f, 0.0f, 0.0f);
}

__global__ void gru32_kernel(const float* __restrict__ x,
                             const float* __restrict__ h,
                             float* __restrict__ out,
                             const int* __restrict__ depth, int iter, int n,
                             const float* __restrict__ Wz, const float* __restrict__ bz,
                             const float* __restrict__ Uz, const float* __restrict__ buz,
                             const float* __restrict__ Wr, const float* __restrict__ br,
                             const float* __restrict__ Ur, const float* __restrict__ bur,
                             const float* __restrict__ Wh, const float* __restrict__ bh,
                             const float* __restrict__ Uh, const float* __restrict__ buh)
{
    __shared__ float sW[6][100];
    __shared__ float sb[3][10];
    const int t = threadIdx.x;
    if (t < 100) {
        sW[0][t] = Wz[t]; sW[1][t] = Uz[t];
        sW[2][t] = Wr[t]; sW[3][t] = Ur[t];
        sW[4][t] = Wh[t]; sW[5][t] = Uh[t];
    }
    if (t < 10) {
        sb[0][t] = bz[t] + buz[t];
        sb[1][t] = br[t] + bur[t];
        sb[2][t] = bh[t] + buh[t];
    }
    __syncthreads();

    int node = blockIdx.x * blockDim.x + t;
    if (node >= n) return;
    const int dep = depth[node];
    const bool active = dep + iter <= 2;
    float xv[DIM], hv[DIM], outv[DIM];
    #pragma unroll
    for (int j = 0; j < DIM; ++j) {
        xv[j] = x[(size_t)node * DIM + j];
        hv[j] = h[(size_t)node * DIM + j];
    }
    if (active) {
        float zz[DIM], rr[DIM];
        #pragma unroll
        for (int i = 0; i < DIM; ++i) {
            float az = sb[0][i], ar = sb[1][i];
            #pragma unroll
            for (int j = 0; j < DIM; ++j) {
                az = fmaf(xv[j], sW[0][i * DIM + j], az);
                az = fmaf(hv[j], sW[1][i * DIM + j], az);
                ar = fmaf(xv[j], sW[2][i * DIM + j], ar);
                ar = fmaf(hv[j], sW[3][i * DIM + j], ar);
            }
            zz[i] = 1.0f / (1.0f + __expf(-az));
            rr[i] = 1.0f / (1.0f + __expf(-ar));
        }
        float rh[DIM];
        #pragma unroll
        for (int j = 0; j < DIM; ++j) rh[j] = rr[j] * hv[j];
        #pragma unroll
        for (int i = 0; i < DIM; ++i) {
            float ah = sb[2][i];
            #pragma unroll
            for (int j = 0; j < DIM; ++j) {
                ah = fmaf(xv[j], sW[4][i * DIM + j], ah);
                ah = fmaf(rh[j], sW[5][i * DIM + j], ah);
            }
            outv[i] = zz[i] * hv[i] + (1.0f - zz[i]) * tanhf(ah);
        }
    } else {
        #pragma unroll
        for (int i = 0; i < DIM; ++i) outv[i] = hv[i];
    }
    if (iter == 0 && dep > 1) {
        #pragma unroll
        for (int i = 0; i < DIM; ++i) outv[i] = 0.0f;
    }
    #pragma unroll
    for (int i = 0; i < DIM; ++i) out[(size_t)node * DIM + i] = outv[i];
}

extern "C" void kernel_launch(void* const* d_in, const int* in_sizes, int n_in,
                              void* d_out, int out_size, void* d_ws, size_t ws_size,
                              hipStream_t stream) {
    const float* h_in  = (const float*)d_in[0];
    const int*   edges = (const int*)d_in[1];
    const int*   depth = (const int*)d_in[2];
    const float* Wz  = (const float*)d_in[3];
    const float* bz  = (const float*)d_in[4];
    const float* Uz  = (const float*)d_in[5];
    const float* buz = (const float*)d_in[6];
    const float* Wr  = (const float*)d_in[7];
    const float* br  = (const float*)d_in[8];
    const float* Ur  = (const float*)d_in[9];
    const float* bur = (const float*)d_in[10];
    const float* Wh  = (const float*)d_in[11];
    const float* bh  = (const float*)d_in[12];
    const float* Uh  = (const float*)d_in[13];
    const float* buh = (const float*)d_in[14];

    const int n  = in_sizes[0] / DIM;       // 500,000
    const int ne = in_sizes[1] / 2;         // 8,000,000
    const int* recv = edges;
    const int* send = edges + ne;

    const int NB = (n + BKT - 1) >> BKT_LOG;
    const size_t meta_words = 2 * NBMAX + 8 + OVFCAP + D2WORDS;
    const size_t need = (size_t)n * 16 * sizeof(uint16_t) * 2        // h16a + h16b
                      + (size_t)NB * CAPB * sizeof(uint32_t)         // bins
                      + meta_words * sizeof(uint32_t);

    const int BLK = 256;

    if (ws_size >= need && n <= (1 << 19) && NB <= NBMAX) {
        uint16_t* h16a = (uint16_t*)d_ws;                       // [n*16]
        uint16_t* h16b = h16a + (size_t)n * 16;                 // [n*16]
        uint32_t* bins = (uint32_t*)(h16b + (size_t)n * 16);    // [NB*CAPB]
        uint32_t* meta = bins + (size_t)NB * CAPB;
        uint32_t* cntF   = meta;
        uint32_t* cntB   = meta + NBMAX;
        uint32_t* ovfc   = meta + 2 * NBMAX;
        uint32_t* ovf    = meta + 2 * NBMAX + 8;
        uint32_t* depth2 = meta + 2 * NBMAX + 8 + OVFCAP;

        const int bin_blocks  = (ne + EPW - 1) / EPW;
        const int node_blocks = (n + NTILE - 1) / NTILE;
        const int pack_blocks = (n + 4095) / 4096;
        const int cnt_tot = 2 * NBMAX + 1;
        const int cnt_blocks = (cnt_tot + 255) / 256;

        prep_kernel<<<pack_blocks + cnt_blocks, BLK, 0, stream>>>(
            depth, depth2, meta, n, pack_blocks, cnt_tot);
        binit_kernel<<<bin_blocks + node_blocks, BLK, 0, stream>>>(
            recv, send, depth2, depth, h_in, h16a,
            cntF, cntB, ovfc, ovf, bins, ne, n, bin_blocks);

        scatgru_kernel<0><<<NB, BLK, 0, stream>>>(
            bins, cntF, cntB, ovfc, ovf, recv, send, depth,
            h16a, h16b, nullptr, n,
            Wz, bz, Uz, buz, Wr, br, Ur, bur, Wh, bh, Uh, buh);

        scatgru_kernel<1><<<NB, BLK, 0, stream>>>(
            bins, cntF, cntB, ovfc, ovf, recv, send, depth,
            h16b, nullptr, (float*)d_out, n,
            Wz, bz, Uz, buz, Wr, br, Ur, bur, Wh, bh, Uh, buh);
    } else {
        // fallback: fp32 global-atomic pipeline, h in d_out, x in ws
        float* x    = (float*)d_ws;
        float* hbuf = (float*)d_out;
        const int nwork = ne * DIM;
        const int edge_blocks = (nwork + BLK - 1) / BLK;
        const int x_tot4 = (n * DIM) / 4;
        const int xz_blocks = (x_tot4 + BLK - 1) / BLK;
        const int nb2 = (n + BLK - 1) / BLK;

        init_mask32_kernel<<<nb2, BLK, 0, stream>>>(h_in, hbuf, depth, n);
        zero_buf_kernel<<<xz_blocks, BLK, 0, stream>>>((float4*)x, x_tot4);
        simple_scatter_kernel<<<edge_blocks, BLK, 0, stream>>>(recv, send, hbuf, x, ne);
        gru32_kernel<<<nb2, BLK, 0, stream>>>(x, hbuf, hbuf, depth, 0, n,
            Wz, bz, Uz, buz, Wr, br, Ur, bur, Wh, bh, Uh, buh);
        zero_buf_kernel<<<xz_blocks, BLK, 0, stream>>>((float4*)x, x_tot4);
        simple_scatter_kernel<<<edge_blocks, BLK, 0, stream>>>(recv, send, hbuf, x, ne);
        gru32_kernel<<<nb2, BLK, 0, stream>>>(x, hbuf, hbuf, depth, 1, n,
            Wz, bz, Uz, buz, Wr, br, Ur, bur, Wh, bh, Uh, buh);
    }
}

// Round 13
// 554.750 us; speedup vs baseline: 1.7602x; 1.1657x over previous
//
#include <hip/hip_runtime.h>
#include <hip/hip_fp16.h>
#include <math.h>
#include <stdint.h>

#define DIM 10
#define NTILE 256
#define BKT_LOG 8
#define BKT 256                   // nodes per bucket == threads per WG
#define NBMAX 2048
#define EPW 2048                  // edges per WG in binning
#define KPT (EPW / 256)
#define CAPB 2816                 // slots per bucket
#define CAPF 1280                 // front region (mean 1024 + ~8 sigma)
#define CAPK (CAPB - CAPF)        // back region  (mean 1280 + ~7 sigma)
#define OVFCAP 32768
#define D2WORDS 32768

// meta (u32): cntF[NBMAX] | cntB[NBMAX] | ovfc[8] | ovf[OVFCAP] | depth2[D2WORDS]
// ws: h16a[n*16 u16] | h16b[n*16 u16] | bins[NB*CAPB u32] | meta

__device__ __forceinline__ float2 cvt2(uint32_t u) {
    __half2 hh = *reinterpret_cast<__half2*>(&u);
    return __half22float2(hh);
}

__device__ __forceinline__ int d2get(const uint32_t* __restrict__ depth2, int node) {
    uint32_t w = depth2[(uint32_t)node >> 4];
    return (int)((w >> ((node & 15) * 2)) & 3u);
}

// ---------------------------------------------------------------------------
// prep: blocks [0,pack_blocks) pack depth into 2-bit table;
//       blocks [pack_blocks, ...) zero the counters.
// ---------------------------------------------------------------------------
__global__ void prep_kernel(const int* __restrict__ depth,
                            uint32_t* __restrict__ depth2,
                            uint32_t* __restrict__ cnts,
                            int n, int pack_blocks, int cnt_tot)
{
    __shared__ int sd[4096];
    const int t = threadIdx.x;
    const int bid = blockIdx.x;
    if (bid < pack_blocks) {
        const int base = bid * 4096;
        for (int i = t; i < 4096; i += 256) {
            int g = base + i;
            sd[i] = (g < n) ? depth[g] : 3;
        }
        __syncthreads();
        const int wbase = base >> 4;
        int wb = wbase + t;
        if (wb * 16 < n) {
            uint32_t v = 0;
            #pragma unroll
            for (int j = 0; j < 16; ++j)
                v |= ((uint32_t)(sd[t * 16 + j] & 3)) << (2 * j);
            depth2[wb] = v;
        }
    } else {
        int i = (bid - pack_blocks) * 256 + t;
        if (i < cnt_tot) cnts[i] = 0;
    }
}

// ---------------------------------------------------------------------------
// binit: blocks [0,bin_blocks) = edge binning; rest = init h16a from h_in.
// ---------------------------------------------------------------------------
__global__ __launch_bounds__(256) void binit_kernel(
                           const int* __restrict__ recv,
                           const int* __restrict__ send,
                           const uint32_t* __restrict__ depth2,
                           const int* __restrict__ depth,
                           const float* __restrict__ h_in,
                           uint16_t* __restrict__ h16a,
                           uint32_t* __restrict__ cntF,
                           uint32_t* __restrict__ cntB,
                           uint32_t* __restrict__ ovfc,
                           uint32_t* __restrict__ ovf,
                           uint32_t* __restrict__ bins,
                           int ne, int n, int bin_blocks)
{
    __shared__ uint32_t u[3 * NBMAX];    // 24 KB
    const int t = threadIdx.x;
    const int bid = blockIdx.x;

    if (bid < bin_blocks) {
        uint32_t* lh  = u;
        uint32_t* wgF = u + NBMAX;
        uint32_t* wgB = u + 2 * NBMAX;
        for (int i = t; i < NBMAX; i += 256) lh[i] = 0;
        __syncthreads();

        const int base = bid * EPW;
        int rA[KPT], sA[KPT];
        #pragma unroll
        for (int k = 0; k < KPT; ++k) {
            int e = base + k * 256 + t;
            if (e < ne) { rA[k] = recv[e]; sA[k] = send[e]; }
            else        { rA[k] = -1;      sA[k] = 0;       }
        }
        int drA[KPT], dsA[KPT];
        #pragma unroll
        for (int k = 0; k < KPT; ++k) {
            if (rA[k] >= 0) { drA[k] = d2get(depth2, rA[k]); dsA[k] = d2get(depth2, sA[k]); }
            else            { drA[k] = 3;                    dsA[k] = 3;                    }
        }
        uint32_t fl = 0;
        #pragma unroll
        for (int k = 0; k < KPT; ++k) {
            if (rA[k] >= 0 && drA[k] <= 2 && dsA[k] <= 2) {
                bool f1 = (drA[k] <= 1) && (dsA[k] <= 1);
                fl |= (f1 ? 3u : 1u) << (2 * k);
                atomicAdd(&lh[rA[k] >> BKT_LOG], f1 ? 1u : 0x10000u);
            }
        }
        __syncthreads();

        for (int i = t; i < NBMAX; i += 256) {
            uint32_t v = lh[i];
            if (v) {
                uint32_t f = v & 0xffffu, kb = v >> 16;
                if (f)  wgF[i] = atomicAdd(&cntF[i], f);
                if (kb) wgB[i] = atomicAdd(&cntB[i], kb);
            }
        }
        __syncthreads();
        for (int i = t; i < NBMAX; i += 256) lh[i] = 0;   // reuse as cursors
        __syncthreads();

        #pragma unroll
        for (int k = 0; k < KPT; ++k) {
            if ((fl >> (2 * k)) & 1u) {
                int r = rA[k], s = sA[k];
                int b = r >> BKT_LOG;
                bool f1 = (fl >> (2 * k)) & 2u;
                uint32_t w = (uint32_t)s | ((uint32_t)(r & (BKT - 1)) << 19)
                           | (f1 ? (1u << 27) : 0u);
                if (f1) {
                    uint32_t o = atomicAdd(&lh[b], 1u) & 0xffffu;
                    uint32_t pos = wgF[b] + o;
                    if (pos < CAPF) bins[(size_t)b * CAPB + pos] = w;
                    else { uint32_t oi = atomicAdd(ovfc, 1u);
                           if (oi < OVFCAP) ovf[oi] = (uint32_t)(base + k * 256 + t); }
                } else {
                    uint32_t o = atomicAdd(&lh[b], 0x10000u) >> 16;
                    uint32_t pos = wgB[b] + o;
                    if (pos < CAPK) bins[(size_t)b * CAPB + (CAPB - 1) - pos] = w;
                    else { uint32_t oi = atomicAdd(ovfc, 1u);
                           if (oi < OVFCAP) ovf[oi] = (uint32_t)(base + k * 256 + t); }
                }
            }
        }
    } else {
        // init: h16a[node] = fp16( (depth<=2) ? h_in[node] : 0 ), pads 0
        float* sh = reinterpret_cast<float*>(u);
        const int tile = bid - bin_blocks;
        const int base = tile * NTILE;

        const long gbase = (long)base * DIM;
        const long glim  = (long)n * DIM;
        for (int idx = t; idx < NTILE * DIM; idx += NTILE) {
            long g = gbase + idx;
            float v = (g < glim) ? h_in[g] : 0.0f;
            sh[(idx / DIM) * 11 + (idx % DIM)] = v;
        }
        __syncthreads();

        const int node = base + t;
        if (node < n && depth[node] > 2) {
            #pragma unroll
            for (int c = 0; c < DIM; ++c) sh[t * 11 + c] = 0.0f;
        }
        __syncthreads();

        uint32_t* o16 = reinterpret_cast<uint32_t*>(h16a);
        const long o16base = (long)base * 8;
        const long o16lim  = (long)n * 8;
        for (int idx = t; idx < NTILE * 8; idx += NTILE) {
            long g = o16base + idx;
            if (g < o16lim) {
                int nl = idx / 8, c2 = idx % 8;
                uint32_t w = 0;
                if (c2 < 5) {
                    __half2 hh = __floats2half2_rn(sh[nl * 11 + 2 * c2],
                                                   sh[nl * 11 + 2 * c2 + 1]);
                    w = *reinterpret_cast<uint32_t*>(&hh);
                }
                o16[g] = w;
            }
        }
    }
}

// ---------------------------------------------------------------------------
// fused scatter + GRU, register-dieted:
//  - simple (unbatched) gather loop          [K=4 proven neutral, -28 VGPR]
//  - GRU: r*h stored in own xl slots, outputs packed incrementally [-30 VGPR]
//  - __launch_bounds__(256,6) caps VGPR ~85 -> 6 WGs/CU
// ---------------------------------------------------------------------------
template<int ITER>
__global__ __launch_bounds__(256, 6) void scatgru_kernel(
                            const uint32_t* __restrict__ bins,
                            const uint32_t* __restrict__ cntF,
                            const uint32_t* __restrict__ cntB,
                            const uint32_t* __restrict__ ovfc,
                            const uint32_t* __restrict__ ovf,
                            const int* __restrict__ recv,
                            const int* __restrict__ send,
                            const int* __restrict__ depth,
                            const uint16_t* __restrict__ hcur,  // stride 16 halfs
                            uint16_t* __restrict__ hnext,       // ITER==0 out
                            float* __restrict__ out32,          // ITER==1 out
                            int n,
                            const float* __restrict__ Wz, const float* __restrict__ bz,
                            const float* __restrict__ Uz, const float* __restrict__ buz,
                            const float* __restrict__ Wr, const float* __restrict__ br,
                            const float* __restrict__ Ur, const float* __restrict__ bur,
                            const float* __restrict__ Wh, const float* __restrict__ bh,
                            const float* __restrict__ Uh, const float* __restrict__ buh)
{
    __shared__ float xl[BKT * DIM];      // 10240 B
    __shared__ float sW[6][100];
    __shared__ float sb[3][10];

    const int t = threadIdx.x;
    if (t < 100) {
        sW[0][t] = Wz[t]; sW[1][t] = Uz[t];
        sW[2][t] = Wr[t]; sW[3][t] = Ur[t];
        sW[4][t] = Wh[t]; sW[5][t] = Uh[t];
    }
    if (t < 10) {
        sb[0][t] = bz[t] + buz[t];
        sb[1][t] = br[t] + bur[t];
        sb[2][t] = bh[t] + buh[t];
    }
    for (int i = t; i < BKT * DIM; i += 256) xl[i] = 0.0f;
    __syncthreads();

    const int b = blockIdx.x;
    const int n0 = b << BKT_LOG;
    const int nb = min(BKT, n - n0);

    const size_t base = (size_t)b * CAPB;
    const int fc = (int)min(cntF[b], (uint32_t)CAPF);
    int tot = fc, boff = 0;
    if (ITER == 0) {
        int bc = (int)min(cntB[b], (uint32_t)CAPK);
        tot = fc + bc;
        boff = CAPB - bc - fc;
    }

    // phase 1: gather + LDS accumulate (simple loop; compiler pipelines)
    for (int i = t; i < tot; i += 256) {
        size_t idx = base + (size_t)((ITER == 0 && i >= fc) ? (i + boff) : i);
        uint32_t w = bins[idx];
        size_t s = (size_t)(w & 0x7FFFFu);
        uint4 q = *reinterpret_cast<const uint4*>(hcur + s * 16);
        uint32_t e8 = *reinterpret_cast<const uint32_t*>(hcur + s * 16 + 8);
        float2 f0 = cvt2(q.x), f1 = cvt2(q.y), f2 = cvt2(q.z), f3 = cvt2(q.w);
        float2 f4 = cvt2(e8);
        float* xr = xl + ((w >> 19) & (BKT - 1)) * DIM;
        atomicAdd(xr + 0, f0.x); atomicAdd(xr + 1, f0.y);
        atomicAdd(xr + 2, f1.x); atomicAdd(xr + 3, f1.y);
        atomicAdd(xr + 4, f2.x); atomicAdd(xr + 5, f2.y);
        atomicAdd(xr + 6, f3.x); atomicAdd(xr + 7, f3.y);
        atomicAdd(xr + 8, f4.x); atomicAdd(xr + 9, f4.y);
    }

    // phase 2: rare overflow edges for this bucket
    {
        const uint32_t cnt = min(*ovfc, (uint32_t)OVFCAP);
        for (uint32_t i = t; i < cnt; i += 256) {
            int e = (int)ovf[i];
            int r = recv[e];
            if ((r >> BKT_LOG) != b) continue;
            int s = send[e];
            if (ITER == 1 && (depth[r] > 1 || depth[s] > 1)) continue;
            uint4 q = *reinterpret_cast<const uint4*>(hcur + (size_t)s * 16);
            uint32_t e8v = *reinterpret_cast<const uint32_t*>(hcur + (size_t)s * 16 + 8);
            float2 f0 = cvt2(q.x), f1 = cvt2(q.y), f2 = cvt2(q.z), f3 = cvt2(q.w);
            float2 f4 = cvt2(e8v);
            float* xr = xl + (r & (BKT - 1)) * DIM;
            atomicAdd(xr + 0, f0.x); atomicAdd(xr + 1, f0.y);
            atomicAdd(xr + 2, f1.x); atomicAdd(xr + 3, f1.y);
            atomicAdd(xr + 4, f2.x); atomicAdd(xr + 5, f2.y);
            atomicAdd(xr + 6, f3.x); atomicAdd(xr + 7, f3.y);
            atomicAdd(xr + 8, f4.x); atomicAdd(xr + 9, f4.y);
        }
    }
    __syncthreads();

    // phase 3: GRU for node n0+t (register-dieted)
    if (t < nb) {
        const int node = n0 + t;
        const int dep = depth[node];
        const bool active = (dep + ITER) <= 2;

        float hv[DIM];
        {
            const uint16_t* hp = hcur + (size_t)node * 16;
            uint4 q = *reinterpret_cast<const uint4*>(hp);
            uint32_t e8v = *reinterpret_cast<const uint32_t*>(hp + 8);
            float2 f0 = cvt2(q.x), f1 = cvt2(q.y), f2 = cvt2(q.z), f3 = cvt2(q.w);
            float2 f4 = cvt2(e8v);
            hv[0] = f0.x; hv[1] = f0.y; hv[2] = f1.x; hv[3] = f1.y;
            hv[4] = f2.x; hv[5] = f2.y; hv[6] = f3.x; hv[7] = f3.y;
            hv[8] = f4.x; hv[9] = f4.y;
        }
        float xv[DIM];
        #pragma unroll
        for (int j = 0; j < DIM; ++j) xv[j] = xl[t * DIM + j];

        float zz[DIM];
        if (active) {
            // pass A: z and r; store r*h into our own xl slots (x consumed)
            #pragma unroll
            for (int i = 0; i < DIM; ++i) {
                float az = sb[0][i];
                float ar = sb[1][i];
                #pragma unroll
                for (int j = 0; j < DIM; ++j) {
                    az = fmaf(xv[j], sW[0][i * DIM + j], az);
                    az = fmaf(hv[j], sW[1][i * DIM + j], az);
                    ar = fmaf(xv[j], sW[2][i * DIM + j], ar);
                    ar = fmaf(hv[j], sW[3][i * DIM + j], ar);
                }
                zz[i] = 1.0f / (1.0f + __expf(-az));
                xl[t * DIM + i] = (1.0f / (1.0f + __expf(-ar))) * hv[i];  // rh
            }
        }

        // pass B: candidate + output, incrementally packed (no outv array)
        if (ITER == 0) {
            uint32_t packed[5];
            float prev = 0.0f;
            #pragma unroll
            for (int i = 0; i < DIM; ++i) {
                float o;
                if (active) {
                    float ah = sb[2][i];
                    #pragma unroll
                    for (int j = 0; j < DIM; ++j) {
                        ah = fmaf(xv[j], sW[4][i * DIM + j], ah);
                        ah = fmaf(xl[t * DIM + j], sW[5][i * DIM + j], ah);
                    }
                    o = zz[i] * hv[i] + (1.0f - zz[i]) * tanhf(ah);
                } else {
                    o = hv[i];
                }
                if (dep > 1) o = 0.0f;     // fold iter-1 mask
                if (i & 1) {
                    __half2 hh = __floats2half2_rn(prev, o);
                    packed[i >> 1] = *reinterpret_cast<uint32_t*>(&hh);
                } else prev = o;
            }
            uint4 o0 = make_uint4(packed[0], packed[1], packed[2], packed[3]);
            uint4 o1 = make_uint4(packed[4], 0u, 0u, 0u);
            *reinterpret_cast<uint4*>(hnext + (size_t)node * 16)     = o0;
            *reinterpret_cast<uint4*>(hnext + (size_t)node * 16 + 8) = o1;
        } else {
            float2* op = reinterpret_cast<float2*>(out32 + (size_t)node * DIM);
            float prev = 0.0f;
            #pragma unroll
            for (int i = 0; i < DIM; ++i) {
                float o;
                if (active) {
                    float ah = sb[2][i];
                    #pragma unroll
                    for (int j = 0; j < DIM; ++j) {
                        ah = fmaf(xv[j], sW[4][i * DIM + j], ah);
                        ah = fmaf(xl[t * DIM + j], sW[5][i * DIM + j], ah);
                    }
                    o = zz[i] * hv[i] + (1.0f - zz[i]) * tanhf(ah);
                } else {
                    o = hv[i];
                }
                if (i & 1) op[i >> 1] = make_float2(prev, o);
                else prev = o;
            }
        }
    }
}

// ---------------------------------------------------------------------------
// fallback path (ws too small / n too large): fp32 global-atomic pipeline
// ---------------------------------------------------------------------------
__global__ void init_mask32_kernel(const float* __restrict__ hsrc,
                                   float* __restrict__ hdst,
                                   const int* __restrict__ depth,
                                   int n)
{
    int node = blockIdx.x * blockDim.x + threadIdx.x;
    if (node >= n) return;
    bool act = depth[node] <= 2;
    const float* s = hsrc + (size_t)node * DIM;
    float* d = hdst + (size_t)node * DIM;
    #pragma unroll
    for (int c = 0; c < DIM; ++c) d[c] = act ? s[c] : 0.0f;
}

__global__ void simple_scatter_kernel(const int* __restrict__ recv,
                                      const int* __restrict__ send,
                                      const float* __restrict__ hm,
                                      float* __restrict__ x,
                                      int ne)
{
    const int tid = blockIdx.x * blockDim.x + threadIdx.x;
    const int e = tid / DIM;
    if (e >= ne) return;
    const int c = tid - e * DIM;
    const int s = send[e];
    const float v = hm[(size_t)s * DIM + c];
    if (v != 0.0f) {
        const int r = recv[e];
        unsafeAtomicAdd(x + (size_t)r * DIM + c, v);
    }
}

__global__ void zero_buf_kernel(float4* __restrict__ p, int tot4) {
    int i = blockIdx.x * blockDim.x + threadIdx.x;
    if (i < tot4) p[i] = make_float4(0.0f, 0.0f, 0.0f, 0.0f);
}

__global__ void gru32_kernel(const float* __restrict__ x,
                             const float* __restrict__ h,
                             float* __restrict__ out,
                             const int* __restrict__ depth, int iter, int n,
                             const float* __restrict__ Wz, const float* __restrict__ bz,
                             const float* __restrict__ Uz, const float* __restrict__ buz,
                             const float* __restrict__ Wr, const float* __restrict__ br,
                             const float* __restrict__ Ur, const float* __restrict__ bur,
                             const float* __restrict__ Wh, const float* __restrict__ bh,
                             const float* __restrict__ Uh, const float* __restrict__ buh)
{
    __shared__ float sW[6][100];
    __shared__ float sb[3][10];
    const int t = threadIdx.x;
    if (t < 100) {
        sW[0][t] = Wz[t]; sW[1][t] = Uz[t];
        sW[2][t] = Wr[t]; sW[3][t] = Ur[t];
        sW[4][t] = Wh[t]; sW[5][t] = Uh[t];
    }
    if (t < 10) {
        sb[0][t] = bz[t] + buz[t];
        sb[1][t] = br[t] + bur[t];
        sb[2][t] = bh[t] + buh[t];
    }
    __syncthreads();

    int node = blockIdx.x * blockDim.x + t;
    if (node >= n) return;
    const int dep = depth[node];
    const bool active = dep + iter <= 2;
    float xv[DIM], hv[DIM], outv[DIM];
    #pragma unroll
    for (int j = 0; j < DIM; ++j) {
        xv[j] = x[(size_t)node * DIM + j];
        hv[j] = h[(size_t)node * DIM + j];
    }
    if (active) {
        float zz[DIM], rr[DIM];
        #pragma unroll
        for (int i = 0; i < DIM; ++i) {
            float az = sb[0][i], ar = sb[1][i];
            #pragma unroll
            for (int j = 0; j < DIM; ++j) {
                az = fmaf(xv[j], sW[0][i * DIM + j], az);
                az = fmaf(hv[j], sW[1][i * DIM + j], az);
                ar = fmaf(xv[j], sW[2][i * DIM + j], ar);
                ar = fmaf(hv[j], sW[3][i * DIM + j], ar);
            }
            zz[i] = 1.0f / (1.0f + __expf(-az));
            rr[i] = 1.0f / (1.0f + __expf(-ar));
        }
        float rh[DIM];
        #pragma unroll
        for (int j = 0; j < DIM; ++j) rh[j] = rr[j] * hv[j];
        #pragma unroll
        for (int i = 0; i < DIM; ++i) {
            float ah = sb[2][i];
            #pragma unroll
            for (int j = 0; j < DIM; ++j) {
                ah = fmaf(xv[j], sW[4][i * DIM + j], ah);
                ah = fmaf(rh[j], sW[5][i * DIM + j], ah);
            }
            outv[i] = zz[i] * hv[i] + (1.0f - zz[i]) * tanhf(ah);
        }
    } else {
        #pragma unroll
        for (int i = 0; i < DIM; ++i) outv[i] = hv[i];
    }
    if (iter == 0 && dep > 1) {
        #pragma unroll
        for (int i = 0; i < DIM; ++i) outv[i] = 0.0f;
    }
    #pragma unroll
    for (int i = 0; i < DIM; ++i) out[(size_t)node * DIM + i] = outv[i];
}

extern "C" void kernel_launch(void* const* d_in, const int* in_sizes, int n_in,
                              void* d_out, int out_size, void* d_ws, size_t ws_size,
                              hipStream_t stream) {
    const float* h_in  = (const float*)d_in[0];
    const int*   edges = (const int*)d_in[1];
    const int*   depth = (const int*)d_in[2];
    const float* Wz  = (const float*)d_in[3];
    const float* bz  = (const float*)d_in[4];
    const float* Uz  = (const float*)d_in[5];
    const float* buz = (const float*)d_in[6];
    const float* Wr  = (const float*)d_in[7];
    const float* br  = (const float*)d_in[8];
    const float* Ur  = (const float*)d_in[9];
    const float* bur = (const float*)d_in[10];
    const float* Wh  = (const float*)d_in[11];
    const float* bh  = (const float*)d_in[12];
    const float* Uh  = (const float*)d_in[13];
    const float* buh = (const float*)d_in[14];

    const int n  = in_sizes[0] / DIM;       // 500,000
    const int ne = in_sizes[1] / 2;         // 8,000,000
    const int* recv = edges;
    const int* send = edges + ne;

    const int NB = (n + BKT - 1) >> BKT_LOG;
    const size_t meta_words = 2 * NBMAX + 8 + OVFCAP + D2WORDS;
    const size_t need = (size_t)n * 16 * sizeof(uint16_t) * 2        // h16a + h16b
                      + (size_t)NB * CAPB * sizeof(uint32_t)         // bins
                      + meta_words * sizeof(uint32_t);

    const int BLK = 256;

    if (ws_size >= need && n <= (1 << 19) && NB <= NBMAX) {
        uint16_t* h16a = (uint16_t*)d_ws;                       // [n*16]
        uint16_t* h16b = h16a + (size_t)n * 16;                 // [n*16]
        uint32_t* bins = (uint32_t*)(h16b + (size_t)n * 16);    // [NB*CAPB]
        uint32_t* meta = bins + (size_t)NB * CAPB;
        uint32_t* cntF   = meta;
        uint32_t* cntB   = meta + NBMAX;
        uint32_t* ovfc   = meta + 2 * NBMAX;
        uint32_t* ovf    = meta + 2 * NBMAX + 8;
        uint32_t* depth2 = meta + 2 * NBMAX + 8 + OVFCAP;

        const int bin_blocks  = (ne + EPW - 1) / EPW;
        const int node_blocks = (n + NTILE - 1) / NTILE;
        const int pack_blocks = (n + 4095) / 4096;
        const int cnt_tot = 2 * NBMAX + 1;
        const int cnt_blocks = (cnt_tot + 255) / 256;

        prep_kernel<<<pack_blocks + cnt_blocks, BLK, 0, stream>>>(
            depth, depth2, meta, n, pack_blocks, cnt_tot);
        binit_kernel<<<bin_blocks + node_blocks, BLK, 0, stream>>>(
            recv, send, depth2, depth, h_in, h16a,
            cntF, cntB, ovfc, ovf, bins, ne, n, bin_blocks);

        scatgru_kernel<0><<<NB, BLK, 0, stream>>>(
            bins, cntF, cntB, ovfc, ovf, recv, send, depth,
            h16a, h16b, nullptr, n,
            Wz, bz, Uz, buz, Wr, br, Ur, bur, Wh, bh, Uh, buh);

        scatgru_kernel<1><<<NB, BLK, 0, stream>>>(
            bins, cntF, cntB, ovfc, ovf, recv, send, depth,
            h16b, nullptr, (float*)d_out, n,
            Wz, bz, Uz, buz, Wr, br, Ur, bur, Wh, bh, Uh, buh);
    } else {
        // fallback: fp32 global-atomic pipeline, h in d_out, x in ws
        float* x    = (float*)d_ws;
        float* hbuf = (float*)d_out;
        const int nwork = ne * DIM;
        const int edge_blocks = (nwork + BLK - 1) / BLK;
        const int x_tot4 = (n * DIM) / 4;
        const int xz_blocks = (x_tot4 + BLK - 1) / BLK;
        const int nb2 = (n + BLK - 1) / BLK;

        init_mask32_kernel<<<nb2, BLK, 0, stream>>>(h_in, hbuf, depth, n);
        zero_buf_kernel<<<xz_blocks, BLK, 0, stream>>>((float4*)x, x_tot4);
        simple_scatter_kernel<<<edge_blocks, BLK, 0, stream>>>(recv, send, hbuf, x, ne);
        gru32_kernel<<<nb2, BLK, 0, stream>>>(x, hbuf, hbuf, depth, 0, n,
            Wz, bz, Uz, buz, Wr, br, Ur, bur, Wh, bh, Uh, buh);
        zero_buf_kernel<<<xz_blocks, BLK, 0, stream>>>((float4*)x, x_tot4);
        simple_scatter_kernel<<<edge_blocks, BLK, 0, stream>>>(recv, send, hbuf, x, ne);
        gru32_kernel<<<nb2, BLK, 0, stream>>>(x, hbuf, hbuf, depth, 1, n,
            Wz, bz, Uz, buz, Wr, br, Ur, bur, Wh, bh, Uh, buh);
    }
}